// Round 6
// baseline (243.483 us; speedup 1.0000x reference)
//
#include <hip/hip_runtime.h>
#include <math.h>
#include <stdint.h>

// PaiNN QM encoder, round 6.
//   U = V_JK @ W1b  (N,3,256)   T = b1 + n_i@W1c + S_JK@W1d  (N,256)
//   per edge: x = silu(T[i] + e_pi@W1a + r_hat.U[i]); m = (silu(x@W2+b2))@w3+b3
// kA1: WAVE-PER-ATOM (stage s -> LDS, logits 2 cols/lane, in-wave softmax,
//      float4 v-stream) -- independent waves overlap VALU and HBM phases.
// kA2u/kA2t: MFMA GEMMs (validated r4/r5).
// kB1: fused geometry + RBF-MFMA + layer2-MFMA + scatter (validated r5).

#define L_DIM 6
#define F_DIM 256
#define FH_DIM 128
#define DRBF 32
#define CUTOFF_F 4.0f
#define PI_F 3.14159265358979323846f

using bf16x8 = __attribute__((ext_vector_type(8))) short;
using f32x4v = __attribute__((ext_vector_type(4))) float;

__device__ __forceinline__ float silu_f(float x){ return x / (1.f + __expf(-x)); }

__device__ __forceinline__ unsigned short f2bf(float f){
    uint32_t u = __float_as_uint(f);
    uint32_t r = (u + 0x7fffu + ((u >> 16) & 1u)) >> 16;   // RNE
    return (unsigned short)r;
}

// ---------------- kA1: wave-per-atom attention + weighted sums ----------------
// Block = 4 waves = 4 atoms. Per wave: stage s (6KB) to LDS; logits GEMM with
// h = lane*2..+1; butterfly reduce + in-wave softmax; float4 v-stream -> bf16 out.
__global__ __launch_bounds__(256) void kA1(
    const float* __restrict__ s_stack, const float* __restrict__ v_stack,
    const float* __restrict__ attn_w1, const float* __restrict__ attn_b1,
    const float* __restrict__ attn_w2,
    unsigned short* __restrict__ VJKb, unsigned short* __restrict__ NISb, int N)
{
    __shared__ float s_l[4][L_DIM * F_DIM];   // 24 KB

    const int t    = threadIdx.x;
    const int w    = t >> 6;
    const int lane = t & 63;
    const int n    = min(blockIdx.x * 4 + w, N - 1);

    // ---- stage this wave's atom s-row (6 float4 per lane, coalesced) ----
    const float* sp = s_stack + (size_t)n * (L_DIM * F_DIM);
    #pragma unroll
    for (int l = 0; l < L_DIM; l++){
        float4 v = *(const float4*)(sp + l * F_DIM + lane * 4);
        *(float4*)&s_l[w][l * F_DIM + lane * 4] = v;
    }
    __syncthreads();   // single barrier; all waves stage simultaneously

    // ---- logits: h-cols h0 = lane*2, lane*2+1 ----
    float acc0[L_DIM], acc1[L_DIM];
    #pragma unroll
    for (int l = 0; l < L_DIM; l++){ acc0[l] = 0.f; acc1[l] = 0.f; }

    const float* w1p = attn_w1 + lane * 2;
    #pragma unroll 4
    for (int f = 0; f < F_DIM; f++){
        float2 wv = *(const float2*)(w1p + (size_t)f * FH_DIM);
        #pragma unroll
        for (int l = 0; l < L_DIM; l++){
            float s = s_l[w][l * F_DIM + f];     // uniform addr -> LDS broadcast
            acc0[l] = fmaf(s, wv.x, acc0[l]);
            acc1[l] = fmaf(s, wv.y, acc1[l]);
        }
    }

    float2 b1v = *(const float2*)(attn_b1 + lane * 2);
    float2 w2v = *(const float2*)(attn_w2 + lane * 2);

    float aw[L_DIM];
    #pragma unroll
    for (int l = 0; l < L_DIM; l++){
        float p = silu_f(acc0[l] + b1v.x) * w2v.x + silu_f(acc1[l] + b1v.y) * w2v.y;
        #pragma unroll
        for (int m = 32; m >= 1; m >>= 1) p += __shfl_xor(p, m, 64);
        aw[l] = p;          // butterfly: every lane holds logit l (attn_b2 dropped)
    }
    // in-wave softmax (redundant on all lanes, 6 elements)
    float mx = aw[0];
    #pragma unroll
    for (int l = 1; l < L_DIM; l++) mx = fmaxf(mx, aw[l]);
    float sum = 0.f;
    #pragma unroll
    for (int l = 0; l < L_DIM; l++){ aw[l] = __expf(aw[l] - mx); sum += aw[l]; }
    const float inv = 1.f / sum;
    #pragma unroll
    for (int l = 0; l < L_DIM; l++) aw[l] *= inv;

    // ---- weighted sums: lane owns features f4 = lane*4 .. +3 (float4) ----
    const float* vp = v_stack + (size_t)n * (L_DIM * 3 * F_DIM) + lane * 4;
    float4 v0 = {0.f,0.f,0.f,0.f}, v1 = {0.f,0.f,0.f,0.f}, v2 = {0.f,0.f,0.f,0.f};
    float4 sj = {0.f,0.f,0.f,0.f};
    #pragma unroll
    for (int l = 0; l < L_DIM; l++){
        const float a = aw[l];
        float4 x0 = *(const float4*)(vp + (size_t)(l*3+0) * F_DIM);
        float4 x1 = *(const float4*)(vp + (size_t)(l*3+1) * F_DIM);
        float4 x2 = *(const float4*)(vp + (size_t)(l*3+2) * F_DIM);
        float4 ss = *(const float4*)&s_l[w][l * F_DIM + lane * 4];
        v0.x = fmaf(a, x0.x, v0.x); v0.y = fmaf(a, x0.y, v0.y);
        v0.z = fmaf(a, x0.z, v0.z); v0.w = fmaf(a, x0.w, v0.w);
        v1.x = fmaf(a, x1.x, v1.x); v1.y = fmaf(a, x1.y, v1.y);
        v1.z = fmaf(a, x1.z, v1.z); v1.w = fmaf(a, x1.w, v1.w);
        v2.x = fmaf(a, x2.x, v2.x); v2.y = fmaf(a, x2.y, v2.y);
        v2.z = fmaf(a, x2.z, v2.z); v2.w = fmaf(a, x2.w, v2.w);
        sj.x = fmaf(a, ss.x, sj.x); sj.y = fmaf(a, ss.y, sj.y);
        sj.z = fmaf(a, ss.z, sj.z); sj.w = fmaf(a, ss.w, sj.w);
    }
    float4 ni;
    ni.x = sqrtf(v0.x*v0.x + v1.x*v1.x + v2.x*v2.x);
    ni.y = sqrtf(v0.y*v0.y + v1.y*v1.y + v2.y*v2.y);
    ni.z = sqrtf(v0.z*v0.z + v1.z*v1.z + v2.z*v2.z);
    ni.w = sqrtf(v0.w*v0.w + v1.w*v1.w + v2.w*v2.w);

    ushort4 o;
    o = (ushort4){f2bf(v0.x), f2bf(v0.y), f2bf(v0.z), f2bf(v0.w)};
    *(ushort4*)&VJKb[((size_t)n*3 + 0) * F_DIM + lane*4] = o;
    o = (ushort4){f2bf(v1.x), f2bf(v1.y), f2bf(v1.z), f2bf(v1.w)};
    *(ushort4*)&VJKb[((size_t)n*3 + 1) * F_DIM + lane*4] = o;
    o = (ushort4){f2bf(v2.x), f2bf(v2.y), f2bf(v2.z), f2bf(v2.w)};
    *(ushort4*)&VJKb[((size_t)n*3 + 2) * F_DIM + lane*4] = o;
    o = (ushort4){f2bf(ni.x), f2bf(ni.y), f2bf(ni.z), f2bf(ni.w)};
    *(ushort4*)&NISb[(size_t)n * 512 + lane*4] = o;
    o = (ushort4){f2bf(sj.x), f2bf(sj.y), f2bf(sj.z), f2bf(sj.w)};
    *(ushort4*)&NISb[(size_t)n * 512 + 256 + lane*4] = o;
}

// ---------------- kPrep: transpose/convert weights to bf16 ----------------
__global__ __launch_bounds__(256) void kPrep(
    const float* __restrict__ msg_w1, const float* __restrict__ msg_w2,
    unsigned short* __restrict__ w1bt, unsigned short* __restrict__ w1cdt,
    unsigned short* __restrict__ w2t)
{
    int idx = blockIdx.x * 256 + threadIdx.x;
    if (idx < 65536){
        int k = idx >> 8, j = idx & 255;
        w1bt[(size_t)j * 256 + k] = f2bf(msg_w1[(size_t)(DRBF + k) * F_DIM + j]);
    } else if (idx < 65536 + 131072){
        int i2 = idx - 65536;
        int k = i2 >> 8, j = i2 & 255;
        w1cdt[(size_t)j * 512 + k] = f2bf(msg_w1[(size_t)(DRBF + 256 + k) * F_DIM + j]);
    } else {
        int i3 = idx - 65536 - 131072;
        int k = i3 >> 7, h = i3 & 127;
        w2t[(size_t)h * 256 + k] = f2bf(msg_w2[(size_t)k * FH_DIM + h]);
    }
}

// ---------------- kA2u: U = VJKb @ W1b (MFMA, validated r4/r5) ----------------
__global__ __launch_bounds__(256) void kA2u(
    const unsigned short* __restrict__ VJKb, const unsigned short* __restrict__ w1bt,
    float* __restrict__ U, int M)
{
    const int t  = threadIdx.x;
    const int l  = t & 63;
    const int w  = t >> 6;
    const int lm = l & 15, lq = l >> 4;

    bf16x8 bfr[4][8];
    #pragma unroll
    for (int ct = 0; ct < 4; ct++)
        #pragma unroll
        for (int kb = 0; kb < 8; kb++)
            bfr[ct][kb] = *(const bf16x8*)(w1bt + (size_t)(w*64 + ct*16 + lm) * 256 + kb*32 + lq*8);

    const int r00 = blockIdx.x * 128;
    #pragma unroll 1
    for (int mt = 0; mt < 8; mt++){
        const int r0 = r00 + mt * 16;
        bf16x8 af[8];
        #pragma unroll
        for (int kb = 0; kb < 8; kb++)
            af[kb] = *(const bf16x8*)(VJKb + (size_t)(r0 + lm) * 256 + kb*32 + lq*8);
        f32x4v acc[4];
        #pragma unroll
        for (int ct = 0; ct < 4; ct++) acc[ct] = (f32x4v){0.f,0.f,0.f,0.f};
        #pragma unroll
        for (int kb = 0; kb < 8; kb++)
            #pragma unroll
            for (int ct = 0; ct < 4; ct++)
                acc[ct] = __builtin_amdgcn_mfma_f32_16x16x32_bf16(af[kb], bfr[ct][kb], acc[ct], 0, 0, 0);
        #pragma unroll
        for (int ct = 0; ct < 4; ct++){
            const int col = w*64 + ct*16 + lm;
            #pragma unroll
            for (int r = 0; r < 4; r++)
                U[(size_t)(r0 + lq*4 + r) * 256 + col] = acc[ct][r];
        }
    }
}

// ---------------- kA2t: T = b1 + NISb @ W1cd (MFMA, K=512, validated r4/r5) ----------------
__global__ __launch_bounds__(256) void kA2t(
    const unsigned short* __restrict__ NISb, const unsigned short* __restrict__ w1cdt,
    const float* __restrict__ msg_b1,
    float* __restrict__ T, int M)
{
    const int t  = threadIdx.x;
    const int l  = t & 63;
    const int w  = t >> 6;
    const int lm = l & 15, lq = l >> 4;

    const int ch = blockIdx.x & 1;
    const int bm = blockIdx.x >> 1;

    bf16x8 bfr[2][16];
    #pragma unroll
    for (int ct = 0; ct < 2; ct++)
        #pragma unroll
        for (int kb = 0; kb < 16; kb++)
            bfr[ct][kb] = *(const bf16x8*)(w1cdt + (size_t)(ch*128 + w*32 + ct*16 + lm) * 512 + kb*32 + lq*8);

    const int r00 = bm * 128;
    #pragma unroll 1
    for (int mt = 0; mt < 8; mt++){
        const int r0 = r00 + mt * 16;
        bf16x8 af[16];
        #pragma unroll
        for (int kb = 0; kb < 16; kb++)
            af[kb] = *(const bf16x8*)(NISb + (size_t)(r0 + lm) * 512 + kb*32 + lq*8);
        f32x4v acc[2];
        #pragma unroll
        for (int ct = 0; ct < 2; ct++) acc[ct] = (f32x4v){0.f,0.f,0.f,0.f};
        #pragma unroll
        for (int kb = 0; kb < 16; kb++)
            #pragma unroll
            for (int ct = 0; ct < 2; ct++)
                acc[ct] = __builtin_amdgcn_mfma_f32_16x16x32_bf16(af[kb], bfr[ct][kb], acc[ct], 0, 0, 0);
        #pragma unroll
        for (int ct = 0; ct < 2; ct++){
            const int col = ch*128 + w*32 + ct*16 + lm;
            const float bias = msg_b1[col];
            #pragma unroll
            for (int r = 0; r < 4; r++)
                T[(size_t)(r0 + lq*4 + r) * 256 + col] = acc[ct][r] + bias;
        }
    }
}

// ---------------- CSR binning ----------------
__global__ __launch_bounds__(256) void kHist(const int* __restrict__ pe, int* __restrict__ cnt, int E){
    int e = blockIdx.x * 256 + threadIdx.x;
    if (e < E) atomicAdd(&cnt[pe[(size_t)e*2]], 1);
}

__global__ __launch_bounds__(1024) void kScan(const int* __restrict__ cnt, int* __restrict__ off, int N){
    __shared__ int sums[1024];
    const int t = threadIdx.x;
    const int base = t * 8;
    int c[8]; int s = 0;
    #pragma unroll
    for (int j = 0; j < 8; j++){
        int v = (base + j < N) ? cnt[base + j] : 0;
        c[j] = s; s += v;
    }
    sums[t] = s;
    __syncthreads();
    for (int d = 1; d < 1024; d <<= 1){
        int v = (t >= d) ? sums[t - d] : 0;
        __syncthreads();
        sums[t] += v;
        __syncthreads();
    }
    int excl = (t == 0) ? 0 : sums[t - 1];
    #pragma unroll
    for (int j = 0; j < 8; j++)
        if (base + j < N) off[base + j] = excl + c[j];
    if (t == 1023) off[N] = sums[1023];
}

__global__ __launch_bounds__(256) void kScatter(const int* __restrict__ pe,
    const int* __restrict__ off, int* __restrict__ pos, int* __restrict__ perm, int E){
    int e = blockIdx.x * 256 + threadIdx.x;
    if (e < E){
        int i = pe[(size_t)e*2];
        int slot = atomicAdd(&pos[i], 1);
        perm[off[i] + slot] = e;
    }
}

// ---------------- kB1: fused geometry + edge MLP + scatter (validated r5) ----------------
__global__ __launch_bounds__(256) void kB1(
    const int* __restrict__ pe, const float* __restrict__ disp,
    const float* __restrict__ cell,
    const float* __restrict__ atom_xyz, const float* __restrict__ probe_xyz,
    const float* __restrict__ U, const float* __restrict__ T,
    const float* __restrict__ msg_w1,
    const unsigned short* __restrict__ w2t, const float* __restrict__ msg_b2,
    const float* __restrict__ msg_w3, const float* __restrict__ msg_b3,
    const int* __restrict__ perm,
    float* __restrict__ rho, int E)
{
    __shared__ unsigned short x_lds[32 * 256];   // 16 KB, XOR-swizzled
    __shared__ unsigned short epi_b[32 * 40];    // 2.5 KB, bf16 A-tile (pad 40)
    __shared__ int   ai_l[32];
    __shared__ int   pp_l[32];
    __shared__ float4 rc4_l[32];
    __shared__ float part[4][32];

    char* xbase = (char*)x_lds;

    const int t  = threadIdx.x;
    const int l  = t & 63;
    const int w  = t >> 6;
    const int lq = l >> 4;
    const int lm = l & 15;

    const float c0 = cell[0], c1 = cell[1], c2 = cell[2];
    const float c3 = cell[3], c4 = cell[4], c5 = cell[5];
    const float c6 = cell[6], c7 = cell[7], c8 = cell[8];

    bf16x8 w1afr[4];
    #pragma unroll
    for (int nt = 0; nt < 4; nt++){
        const int col = w*64 + nt*16 + lm;
        bf16x8 v;
        #pragma unroll
        for (int j = 0; j < 8; j++)
            v[j] = (short)f2bf(msg_w1[(size_t)(lq*8 + j) * F_DIM + col]);
        w1afr[nt] = v;
    }

    bf16x8 bfr[2][8];
    #pragma unroll
    for (int nt2 = 0; nt2 < 2; nt2++){
        const int h = w*32 + nt2*16 + lm;
        #pragma unroll
        for (int kb = 0; kb < 8; kb++)
            bfr[nt2][kb] = *(const bf16x8*)(w2t + (size_t)h * F_DIM + kb*32 + lq*8);
    }
    const float b2v0 = msg_b2[w*32 + lm];
    const float b2v1 = msg_b2[w*32 + 16 + lm];
    const float w3v0 = msg_w3[w*32 + lm];
    const float w3v1 = msg_w3[w*32 + 16 + lm];
    const float b3   = msg_b3[0];

    const int e0 = blockIdx.x * 128;

    for (int bb = 0; bb < 4; bb++){
        const int e0b = e0 + bb * 32;

        {
            const int slot = t >> 3, q = t & 7;
            const int s  = min(e0b + slot, E - 1);
            const int ee = perm[s];
            const int ia = pe[(size_t)ee*2];
            const int ip = pe[(size_t)ee*2 + 1];
            const float d0 = disp[(size_t)ee*3], d1 = disp[(size_t)ee*3+1], d2 = disp[(size_t)ee*3+2];
            const float sx = d0*c0 + d1*c3 + d2*c6;
            const float sy = d0*c1 + d1*c4 + d2*c7;
            const float sz = d0*c2 + d1*c5 + d2*c8;
            const float dx = probe_xyz[(size_t)ip*3+0] - (atom_xyz[(size_t)ia*3+0] + sx);
            const float dy = probe_xyz[(size_t)ip*3+1] - (atom_xyz[(size_t)ia*3+1] + sy);
            const float dz = probe_xyz[(size_t)ip*3+2] - (atom_xyz[(size_t)ia*3+2] + sz);
            const float dist = sqrtf(dx*dx + dy*dy + dz*dz);
            const float inv  = 1.f / (dist + 1e-8f);
            const float base = dist * (PI_F / CUTOFF_F);
            ushort4 eb;
            eb.x = f2bf(__sinf(base * (float)(q*4 + 1)) * inv);
            eb.y = f2bf(__sinf(base * (float)(q*4 + 2)) * inv);
            eb.z = f2bf(__sinf(base * (float)(q*4 + 3)) * inv);
            eb.w = f2bf(__sinf(base * (float)(q*4 + 4)) * inv);
            *(ushort4*)&epi_b[slot*40 + q*4] = eb;
            if (q == 0){
                ai_l[slot] = ia;
                pp_l[slot] = ip;
                float cw = (dist < CUTOFF_F) ? 0.5f * (__cosf(base) + 1.f) : 0.f;
                rc4_l[slot] = (float4){dx*inv, dy*inv, dz*inv, cw};
            }
        }
        __syncthreads();

        f32x4v pacc[2][4];
        #pragma unroll
        for (int mt = 0; mt < 2; mt++)
            #pragma unroll
            for (int nt = 0; nt < 4; nt++) pacc[mt][nt] = (f32x4v){0.f,0.f,0.f,0.f};
        #pragma unroll
        for (int mt = 0; mt < 2; mt++){
            const bf16x8 af = *(const bf16x8*)&epi_b[(mt*16 + lm)*40 + lq*8];
            #pragma unroll
            for (int nt = 0; nt < 4; nt++)
                pacc[mt][nt] = __builtin_amdgcn_mfma_f32_16x16x32_bf16(af, w1afr[nt], pacc[mt][nt], 0, 0, 0);
        }

        #pragma unroll
        for (int mt = 0; mt < 2; mt++){
            #pragma unroll
            for (int r = 0; r < 4; r++){
                const int e = mt*16 + lq*4 + r;
                const int i = ai_l[e];
                const float4 rc = rc4_l[e];
                const float* Tp = T + (size_t)i * F_DIM;
                const float* Up = U + (size_t)i * (3*F_DIM);
                #pragma unroll
                for (int nt = 0; nt < 4; nt++){
                    const int col = w*64 + nt*16 + lm;
                    float z = pacc[mt][nt][r] + Tp[col];
                    z = fmaf(rc.x, Up[col],           z);
                    z = fmaf(rc.y, Up[F_DIM + col],   z);
                    z = fmaf(rc.z, Up[2*F_DIM + col], z);
                    const int wofs = e*512 + ((col*2) ^ ((e & 7) << 4));
                    *(unsigned short*)(xbase + wofs) = f2bf(silu_f(z));
                }
            }
        }
        __syncthreads();

        f32x4v acc00 = {0.f,0.f,0.f,0.f}, acc01 = {0.f,0.f,0.f,0.f};
        f32x4v acc10 = {0.f,0.f,0.f,0.f}, acc11 = {0.f,0.f,0.f,0.f};
        const int eA0 = lm;
        const int eA1 = 16 + lm;
        #pragma unroll
        for (int kb = 0; kb < 8; kb++){
            const int ko = kb*64 + lq*16;
            bf16x8 af0 = *(const bf16x8*)(xbase + eA0*512 + (ko ^ ((eA0 & 7) << 4)));
            bf16x8 af1 = *(const bf16x8*)(xbase + eA1*512 + (ko ^ ((eA1 & 7) << 4)));
            acc00 = __builtin_amdgcn_mfma_f32_16x16x32_bf16(af0, bfr[0][kb], acc00, 0, 0, 0);
            acc01 = __builtin_amdgcn_mfma_f32_16x16x32_bf16(af0, bfr[1][kb], acc01, 0, 0, 0);
            acc10 = __builtin_amdgcn_mfma_f32_16x16x32_bf16(af1, bfr[0][kb], acc10, 0, 0, 0);
            acc11 = __builtin_amdgcn_mfma_f32_16x16x32_bf16(af1, bfr[1][kb], acc11, 0, 0, 0);
        }

        float pr0[4], pr1[4];
        #pragma unroll
        for (int r = 0; r < 4; r++){
            pr0[r] = silu_f(acc00[r] + b2v0) * w3v0 + silu_f(acc01[r] + b2v1) * w3v1;
            pr1[r] = silu_f(acc10[r] + b2v0) * w3v0 + silu_f(acc11[r] + b2v1) * w3v1;
        }
        #pragma unroll
        for (int r = 0; r < 4; r++){
            #pragma unroll
            for (int m = 8; m >= 1; m >>= 1){
                pr0[r] += __shfl_xor(pr0[r], m, 64);
                pr1[r] += __shfl_xor(pr1[r], m, 64);
            }
        }
        if (lm == 0){
            #pragma unroll
            for (int r = 0; r < 4; r++){
                part[w][lq*4 + r]      = pr0[r];
                part[w][16 + lq*4 + r] = pr1[r];
            }
        }
        __syncthreads();

        if (t < 32 && (e0b + t) < E){
            float tot = part[0][t] + part[1][t] + part[2][t] + part[3][t] + b3;
            atomicAdd(&rho[pp_l[t]], tot * rc4_l[t].w);
        }
        __syncthreads();
    }
}

extern "C" void kernel_launch(void* const* d_in, const int* in_sizes, int n_in,
                              void* d_out, int out_size, void* d_ws, size_t ws_size,
                              hipStream_t stream)
{
    const float* s_stack   = (const float*)d_in[0];
    const float* v_stack   = (const float*)d_in[1];
    const float* atom_xyz  = (const float*)d_in[2];
    const float* probe_xyz = (const float*)d_in[3];
    const float* cell      = (const float*)d_in[4];
    const float* disp      = (const float*)d_in[5];
    const float* attn_w1   = (const float*)d_in[6];
    const float* attn_b1   = (const float*)d_in[7];
    const float* attn_w2   = (const float*)d_in[8];
    const float* msg_w1    = (const float*)d_in[10];
    const float* msg_b1    = (const float*)d_in[11];
    const float* msg_w2    = (const float*)d_in[12];
    const float* msg_b2    = (const float*)d_in[13];
    const float* msg_w3    = (const float*)d_in[14];
    const float* msg_b3    = (const float*)d_in[15];
    const int*   pe        = (const int*)d_in[16];

    const int N = in_sizes[0] / (L_DIM * F_DIM);
    const int E = in_sizes[16] / 2;
    const int P = out_size;
    const size_t NF = (size_t)N * F_DIM;

    float* ws = (float*)d_ws;
    unsigned short* VJKb = (unsigned short*)ws;          // 3N x 256 bf16  (1.5 NF floats)
    unsigned short* NISb = VJKb + 3*NF;                  // N x 512 bf16   (1.0 NF floats)
    float* Ubuf = ws + (5*NF)/2;                         // 3N x 256 f32
    float* Tbuf = Ubuf + 3*NF;                           // N x 256 f32
    unsigned short* w1bt  = (unsigned short*)(Tbuf + NF);  // 256x256 bf16
    unsigned short* w1cdt = w1bt + 65536;                  // 256x512 bf16
    unsigned short* w2t   = w1cdt + 131072;                // 128x256 bf16
    int* cnt  = (int*)(w2t + 32768);
    int* pos  = cnt + N;
    int* offs = pos + N;
    int* perm = offs + N + 1;

    hipMemsetAsync(d_out, 0, (size_t)P * sizeof(float), stream);
    hipMemsetAsync(cnt, 0, 2 * (size_t)N * sizeof(int), stream);

    kPrep<<<896, 256, 0, stream>>>(msg_w1, msg_w2, w1bt, w1cdt, w2t);

    kA1<<<(N + 3) / 4, 256, 0, stream>>>(s_stack, v_stack, attn_w1, attn_b1, attn_w2,
                                         VJKb, NISb, N);

    kA2u<<<(3 * N) / 128, 256, 0, stream>>>(VJKb, w1bt, Ubuf, 3 * N);
    kA2t<<<(N / 128) * 2, 256, 0, stream>>>(NISb, w1cdt, msg_b1, Tbuf, N);

    const int gE = (E + 255) / 256;
    kHist<<<gE, 256, 0, stream>>>(pe, cnt, E);
    kScan<<<1, 1024, 0, stream>>>(cnt, offs, N);
    kScatter<<<gE, 256, 0, stream>>>(pe, offs, pos, perm, E);

    kB1<<<(E + 127) / 128, 256, 0, stream>>>(pe, disp, cell, atom_xyz, probe_xyz,
                                             Ubuf, Tbuf, msg_w1,
                                             w2t, msg_b2, msg_w3, msg_b3,
                                             perm, (float*)d_out, E);
}

// Round 7
// 208.675 us; speedup vs baseline: 1.1668x; 1.1668x over previous
//
#include <hip/hip_runtime.h>
#include <math.h>
#include <stdint.h>

// PaiNN QM encoder, round 7.
//   U = V_JK @ W1b  (N,3,256)   T = b1 + n_i@W1c + S_JK@W1d  (N,256)
//   per edge: x = silu(T[i] + e_pi@W1a + r_hat.U[i]); m = (silu(x@W2+b2))@w3+b3
// kL: attention logits via MFMA (s as (6N,256) @ attn_w1, silu, .w2 reduce).
// kW: wave-per-atom softmax + float4 weighted-sum stream (r6's proven path).
// kA2u/kA2t: MFMA GEMMs (validated r4-r6). kB1: fused edge MLP (validated r5/r6).

#define L_DIM 6
#define F_DIM 256
#define FH_DIM 128
#define DRBF 32
#define CUTOFF_F 4.0f
#define PI_F 3.14159265358979323846f

using bf16x8 = __attribute__((ext_vector_type(8))) short;
using f32x4v = __attribute__((ext_vector_type(4))) float;

__device__ __forceinline__ float silu_f(float x){ return x / (1.f + __expf(-x)); }

__device__ __forceinline__ unsigned short f2bf(float f){
    uint32_t u = __float_as_uint(f);
    uint32_t r = (u + 0x7fffu + ((u >> 16) & 1u)) >> 16;   // RNE
    return (unsigned short)r;
}

// ---------------- kPrep: transpose/convert weights to bf16 ----------------
// w1bt[j][k]=W1b[k][j]; w1cdt[j][k]=W1cd[k][j]; w2t[h][k]=W2[k][h]; wA1t[j][k]=attn_w1[k][j]
__global__ __launch_bounds__(256) void kPrep(
    const float* __restrict__ msg_w1, const float* __restrict__ msg_w2,
    const float* __restrict__ attn_w1,
    unsigned short* __restrict__ w1bt, unsigned short* __restrict__ w1cdt,
    unsigned short* __restrict__ w2t, unsigned short* __restrict__ wA1t)
{
    int idx = blockIdx.x * 256 + threadIdx.x;
    if (idx < 65536){
        int k = idx >> 8, j = idx & 255;
        w1bt[(size_t)j * 256 + k] = f2bf(msg_w1[(size_t)(DRBF + k) * F_DIM + j]);
    } else if (idx < 196608){
        int i2 = idx - 65536;
        int k = i2 >> 8, j = i2 & 255;
        w1cdt[(size_t)j * 512 + k] = f2bf(msg_w1[(size_t)(DRBF + 256 + k) * F_DIM + j]);
    } else if (idx < 229376){
        int i3 = idx - 196608;
        int k = i3 >> 7, h = i3 & 127;
        w2t[(size_t)h * 256 + k] = f2bf(msg_w2[(size_t)k * FH_DIM + h]);
    } else {
        int i4 = idx - 229376;                 // [0, 32768)
        int j = i4 >> 8, k = i4 & 255;         // j: col 0..127, k: 0..255
        wA1t[(size_t)j * 256 + k] = f2bf(attn_w1[(size_t)k * FH_DIM + j]);
    }
}

// ---------------- kL: logits = (silu(s2d @ W1 + b1)).w2  (MFMA) ----------------
// s2d = s_stack as (6N, 256). Block = 64 rows (4 m-tiles), wave w = cols w*32..+32.
__global__ __launch_bounds__(256) void kL(
    const float* __restrict__ s2d, const unsigned short* __restrict__ wA1t,
    const float* __restrict__ attn_b1, const float* __restrict__ attn_w2,
    float* __restrict__ LG)
{
    __shared__ float part[4][64];

    const int t  = threadIdx.x;
    const int l  = t & 63;
    const int w  = t >> 6;
    const int lm = l & 15, lq = l >> 4;

    bf16x8 bfr[2][8];
    #pragma unroll
    for (int nt2 = 0; nt2 < 2; nt2++){
        const int col = w*32 + nt2*16 + lm;
        #pragma unroll
        for (int kb = 0; kb < 8; kb++)
            bfr[nt2][kb] = *(const bf16x8*)(wA1t + (size_t)col * 256 + kb*32 + lq*8);
    }
    const float b1a = attn_b1[w*32 + lm];
    const float b1b = attn_b1[w*32 + 16 + lm];
    const float w2a = attn_w2[w*32 + lm];
    const float w2b = attn_w2[w*32 + 16 + lm];

    const int r00 = blockIdx.x * 64;

    #pragma unroll
    for (int mt = 0; mt < 4; mt++){
        const int r0 = r00 + mt * 16;
        bf16x8 af[8];
        #pragma unroll
        for (int kb = 0; kb < 8; kb++){
            const float* ap = s2d + (size_t)(r0 + lm) * 256 + kb*32 + lq*8;
            float4 fa = *(const float4*)ap;
            float4 fb = *(const float4*)(ap + 4);
            bf16x8 v;
            v[0] = (short)f2bf(fa.x); v[1] = (short)f2bf(fa.y);
            v[2] = (short)f2bf(fa.z); v[3] = (short)f2bf(fa.w);
            v[4] = (short)f2bf(fb.x); v[5] = (short)f2bf(fb.y);
            v[6] = (short)f2bf(fb.z); v[7] = (short)f2bf(fb.w);
            af[kb] = v;
        }
        f32x4v a0 = {0.f,0.f,0.f,0.f}, a1 = {0.f,0.f,0.f,0.f};
        #pragma unroll
        for (int kb = 0; kb < 8; kb++){
            a0 = __builtin_amdgcn_mfma_f32_16x16x32_bf16(af[kb], bfr[0][kb], a0, 0, 0, 0);
            a1 = __builtin_amdgcn_mfma_f32_16x16x32_bf16(af[kb], bfr[1][kb], a1, 0, 0, 0);
        }
        #pragma unroll
        for (int r = 0; r < 4; r++){
            float p = silu_f(a0[r] + b1a) * w2a + silu_f(a1[r] + b1b) * w2b;
            #pragma unroll
            for (int m = 8; m >= 1; m >>= 1) p += __shfl_xor(p, m, 64);
            if (lm == 0) part[w][mt*16 + lq*4 + r] = p;
        }
    }
    __syncthreads();
    if (t < 64)
        LG[r00 + t] = part[0][t] + part[1][t] + part[2][t] + part[3][t];
}

// ---------------- kW: wave-per-atom softmax + weighted-sum stream ----------------
__global__ __launch_bounds__(256) void kW(
    const float* __restrict__ s_stack, const float* __restrict__ v_stack,
    const float* __restrict__ LG,
    unsigned short* __restrict__ VJKb, unsigned short* __restrict__ NISb, int N)
{
    const int t    = threadIdx.x;
    const int w    = t >> 6;
    const int lane = t & 63;
    const int n    = min(blockIdx.x * 4 + w, N - 1);

    // softmax from raw logits (wave-uniform scalar loads)
    float aw[L_DIM];
    #pragma unroll
    for (int l = 0; l < L_DIM; l++) aw[l] = LG[(size_t)n * L_DIM + l];
    float mx = aw[0];
    #pragma unroll
    for (int l = 1; l < L_DIM; l++) mx = fmaxf(mx, aw[l]);
    float sum = 0.f;
    #pragma unroll
    for (int l = 0; l < L_DIM; l++){ aw[l] = __expf(aw[l] - mx); sum += aw[l]; }
    const float inv = 1.f / sum;
    #pragma unroll
    for (int l = 0; l < L_DIM; l++) aw[l] *= inv;

    // weighted sums: lane owns features lane*4..+3 (float4)
    const float* sp = s_stack + (size_t)n * (L_DIM * F_DIM) + lane * 4;
    const float* vp = v_stack + (size_t)n * (L_DIM * 3 * F_DIM) + lane * 4;
    float4 v0 = {0.f,0.f,0.f,0.f}, v1 = {0.f,0.f,0.f,0.f}, v2 = {0.f,0.f,0.f,0.f};
    float4 sj = {0.f,0.f,0.f,0.f};
    #pragma unroll
    for (int l = 0; l < L_DIM; l++){
        const float a = aw[l];
        float4 ss = *(const float4*)(sp + (size_t)l * F_DIM);
        float4 x0 = *(const float4*)(vp + (size_t)(l*3+0) * F_DIM);
        float4 x1 = *(const float4*)(vp + (size_t)(l*3+1) * F_DIM);
        float4 x2 = *(const float4*)(vp + (size_t)(l*3+2) * F_DIM);
        v0.x = fmaf(a, x0.x, v0.x); v0.y = fmaf(a, x0.y, v0.y);
        v0.z = fmaf(a, x0.z, v0.z); v0.w = fmaf(a, x0.w, v0.w);
        v1.x = fmaf(a, x1.x, v1.x); v1.y = fmaf(a, x1.y, v1.y);
        v1.z = fmaf(a, x1.z, v1.z); v1.w = fmaf(a, x1.w, v1.w);
        v2.x = fmaf(a, x2.x, v2.x); v2.y = fmaf(a, x2.y, v2.y);
        v2.z = fmaf(a, x2.z, v2.z); v2.w = fmaf(a, x2.w, v2.w);
        sj.x = fmaf(a, ss.x, sj.x); sj.y = fmaf(a, ss.y, sj.y);
        sj.z = fmaf(a, ss.z, sj.z); sj.w = fmaf(a, ss.w, sj.w);
    }
    float4 ni;
    ni.x = sqrtf(v0.x*v0.x + v1.x*v1.x + v2.x*v2.x);
    ni.y = sqrtf(v0.y*v0.y + v1.y*v1.y + v2.y*v2.y);
    ni.z = sqrtf(v0.z*v0.z + v1.z*v1.z + v2.z*v2.z);
    ni.w = sqrtf(v0.w*v0.w + v1.w*v1.w + v2.w*v2.w);

    ushort4 o;
    o = (ushort4){f2bf(v0.x), f2bf(v0.y), f2bf(v0.z), f2bf(v0.w)};
    *(ushort4*)&VJKb[((size_t)n*3 + 0) * F_DIM + lane*4] = o;
    o = (ushort4){f2bf(v1.x), f2bf(v1.y), f2bf(v1.z), f2bf(v1.w)};
    *(ushort4*)&VJKb[((size_t)n*3 + 1) * F_DIM + lane*4] = o;
    o = (ushort4){f2bf(v2.x), f2bf(v2.y), f2bf(v2.z), f2bf(v2.w)};
    *(ushort4*)&VJKb[((size_t)n*3 + 2) * F_DIM + lane*4] = o;
    o = (ushort4){f2bf(ni.x), f2bf(ni.y), f2bf(ni.z), f2bf(ni.w)};
    *(ushort4*)&NISb[(size_t)n * 512 + lane*4] = o;
    o = (ushort4){f2bf(sj.x), f2bf(sj.y), f2bf(sj.z), f2bf(sj.w)};
    *(ushort4*)&NISb[(size_t)n * 512 + 256 + lane*4] = o;
}

// ---------------- kA2u: U = VJKb @ W1b (MFMA, validated r4-r6) ----------------
__global__ __launch_bounds__(256) void kA2u(
    const unsigned short* __restrict__ VJKb, const unsigned short* __restrict__ w1bt,
    float* __restrict__ U, int M)
{
    const int t  = threadIdx.x;
    const int l  = t & 63;
    const int w  = t >> 6;
    const int lm = l & 15, lq = l >> 4;

    bf16x8 bfr[4][8];
    #pragma unroll
    for (int ct = 0; ct < 4; ct++)
        #pragma unroll
        for (int kb = 0; kb < 8; kb++)
            bfr[ct][kb] = *(const bf16x8*)(w1bt + (size_t)(w*64 + ct*16 + lm) * 256 + kb*32 + lq*8);

    const int r00 = blockIdx.x * 128;
    #pragma unroll 1
    for (int mt = 0; mt < 8; mt++){
        const int r0 = r00 + mt * 16;
        bf16x8 af[8];
        #pragma unroll
        for (int kb = 0; kb < 8; kb++)
            af[kb] = *(const bf16x8*)(VJKb + (size_t)(r0 + lm) * 256 + kb*32 + lq*8);
        f32x4v acc[4];
        #pragma unroll
        for (int ct = 0; ct < 4; ct++) acc[ct] = (f32x4v){0.f,0.f,0.f,0.f};
        #pragma unroll
        for (int kb = 0; kb < 8; kb++)
            #pragma unroll
            for (int ct = 0; ct < 4; ct++)
                acc[ct] = __builtin_amdgcn_mfma_f32_16x16x32_bf16(af[kb], bfr[ct][kb], acc[ct], 0, 0, 0);
        #pragma unroll
        for (int ct = 0; ct < 4; ct++){
            const int col = w*64 + ct*16 + lm;
            #pragma unroll
            for (int r = 0; r < 4; r++)
                U[(size_t)(r0 + lq*4 + r) * 256 + col] = acc[ct][r];
        }
    }
}

// ---------------- kA2t: T = b1 + NISb @ W1cd (MFMA, K=512, validated r4-r6) ----------------
__global__ __launch_bounds__(256) void kA2t(
    const unsigned short* __restrict__ NISb, const unsigned short* __restrict__ w1cdt,
    const float* __restrict__ msg_b1,
    float* __restrict__ T, int M)
{
    const int t  = threadIdx.x;
    const int l  = t & 63;
    const int w  = t >> 6;
    const int lm = l & 15, lq = l >> 4;

    const int ch = blockIdx.x & 1;
    const int bm = blockIdx.x >> 1;

    bf16x8 bfr[2][16];
    #pragma unroll
    for (int ct = 0; ct < 2; ct++)
        #pragma unroll
        for (int kb = 0; kb < 16; kb++)
            bfr[ct][kb] = *(const bf16x8*)(w1cdt + (size_t)(ch*128 + w*32 + ct*16 + lm) * 512 + kb*32 + lq*8);

    const int r00 = bm * 128;
    #pragma unroll 1
    for (int mt = 0; mt < 8; mt++){
        const int r0 = r00 + mt * 16;
        bf16x8 af[16];
        #pragma unroll
        for (int kb = 0; kb < 16; kb++)
            af[kb] = *(const bf16x8*)(NISb + (size_t)(r0 + lm) * 512 + kb*32 + lq*8);
        f32x4v acc[2];
        #pragma unroll
        for (int ct = 0; ct < 2; ct++) acc[ct] = (f32x4v){0.f,0.f,0.f,0.f};
        #pragma unroll
        for (int kb = 0; kb < 16; kb++)
            #pragma unroll
            for (int ct = 0; ct < 2; ct++)
                acc[ct] = __builtin_amdgcn_mfma_f32_16x16x32_bf16(af[kb], bfr[ct][kb], acc[ct], 0, 0, 0);
        #pragma unroll
        for (int ct = 0; ct < 2; ct++){
            const int col = ch*128 + w*32 + ct*16 + lm;
            const float bias = msg_b1[col];
            #pragma unroll
            for (int r = 0; r < 4; r++)
                T[(size_t)(r0 + lq*4 + r) * 256 + col] = acc[ct][r] + bias;
        }
    }
}

// ---------------- CSR binning ----------------
__global__ __launch_bounds__(256) void kHist(const int* __restrict__ pe, int* __restrict__ cnt, int E){
    int e = blockIdx.x * 256 + threadIdx.x;
    if (e < E) atomicAdd(&cnt[pe[(size_t)e*2]], 1);
}

__global__ __launch_bounds__(1024) void kScan(const int* __restrict__ cnt, int* __restrict__ off, int N){
    __shared__ int sums[1024];
    const int t = threadIdx.x;
    const int base = t * 8;
    int c[8]; int s = 0;
    #pragma unroll
    for (int j = 0; j < 8; j++){
        int v = (base + j < N) ? cnt[base + j] : 0;
        c[j] = s; s += v;
    }
    sums[t] = s;
    __syncthreads();
    for (int d = 1; d < 1024; d <<= 1){
        int v = (t >= d) ? sums[t - d] : 0;
        __syncthreads();
        sums[t] += v;
        __syncthreads();
    }
    int excl = (t == 0) ? 0 : sums[t - 1];
    #pragma unroll
    for (int j = 0; j < 8; j++)
        if (base + j < N) off[base + j] = excl + c[j];
    if (t == 1023) off[N] = sums[1023];
}

__global__ __launch_bounds__(256) void kScatter(const int* __restrict__ pe,
    const int* __restrict__ off, int* __restrict__ pos, int* __restrict__ perm, int E){
    int e = blockIdx.x * 256 + threadIdx.x;
    if (e < E){
        int i = pe[(size_t)e*2];
        int slot = atomicAdd(&pos[i], 1);
        perm[off[i] + slot] = e;
    }
}

// ---------------- kB1: fused geometry + edge MLP + scatter (validated r5/r6) ----------------
__global__ __launch_bounds__(256) void kB1(
    const int* __restrict__ pe, const float* __restrict__ disp,
    const float* __restrict__ cell,
    const float* __restrict__ atom_xyz, const float* __restrict__ probe_xyz,
    const float* __restrict__ U, const float* __restrict__ T,
    const float* __restrict__ msg_w1,
    const unsigned short* __restrict__ w2t, const float* __restrict__ msg_b2,
    const float* __restrict__ msg_w3, const float* __restrict__ msg_b3,
    const int* __restrict__ perm,
    float* __restrict__ rho, int E)
{
    __shared__ unsigned short x_lds[32 * 256];   // 16 KB, XOR-swizzled
    __shared__ unsigned short epi_b[32 * 40];    // 2.5 KB, bf16 A-tile (pad 40)
    __shared__ int   ai_l[32];
    __shared__ int   pp_l[32];
    __shared__ float4 rc4_l[32];
    __shared__ float part[4][32];

    char* xbase = (char*)x_lds;

    const int t  = threadIdx.x;
    const int l  = t & 63;
    const int w  = t >> 6;
    const int lq = l >> 4;
    const int lm = l & 15;

    const float c0 = cell[0], c1 = cell[1], c2 = cell[2];
    const float c3 = cell[3], c4 = cell[4], c5 = cell[5];
    const float c6 = cell[6], c7 = cell[7], c8 = cell[8];

    bf16x8 w1afr[4];
    #pragma unroll
    for (int nt = 0; nt < 4; nt++){
        const int col = w*64 + nt*16 + lm;
        bf16x8 v;
        #pragma unroll
        for (int j = 0; j < 8; j++)
            v[j] = (short)f2bf(msg_w1[(size_t)(lq*8 + j) * F_DIM + col]);
        w1afr[nt] = v;
    }

    bf16x8 bfr[2][8];
    #pragma unroll
    for (int nt2 = 0; nt2 < 2; nt2++){
        const int h = w*32 + nt2*16 + lm;
        #pragma unroll
        for (int kb = 0; kb < 8; kb++)
            bfr[nt2][kb] = *(const bf16x8*)(w2t + (size_t)h * F_DIM + kb*32 + lq*8);
    }
    const float b2v0 = msg_b2[w*32 + lm];
    const float b2v1 = msg_b2[w*32 + 16 + lm];
    const float w3v0 = msg_w3[w*32 + lm];
    const float w3v1 = msg_w3[w*32 + 16 + lm];
    const float b3   = msg_b3[0];

    const int e0 = blockIdx.x * 128;

    for (int bb = 0; bb < 4; bb++){
        const int e0b = e0 + bb * 32;

        {
            const int slot = t >> 3, q = t & 7;
            const int s  = min(e0b + slot, E - 1);
            const int ee = perm[s];
            const int ia = pe[(size_t)ee*2];
            const int ip = pe[(size_t)ee*2 + 1];
            const float d0 = disp[(size_t)ee*3], d1 = disp[(size_t)ee*3+1], d2 = disp[(size_t)ee*3+2];
            const float sx = d0*c0 + d1*c3 + d2*c6;
            const float sy = d0*c1 + d1*c4 + d2*c7;
            const float sz = d0*c2 + d1*c5 + d2*c8;
            const float dx = probe_xyz[(size_t)ip*3+0] - (atom_xyz[(size_t)ia*3+0] + sx);
            const float dy = probe_xyz[(size_t)ip*3+1] - (atom_xyz[(size_t)ia*3+1] + sy);
            const float dz = probe_xyz[(size_t)ip*3+2] - (atom_xyz[(size_t)ia*3+2] + sz);
            const float dist = sqrtf(dx*dx + dy*dy + dz*dz);
            const float inv  = 1.f / (dist + 1e-8f);
            const float base = dist * (PI_F / CUTOFF_F);
            ushort4 eb;
            eb.x = f2bf(__sinf(base * (float)(q*4 + 1)) * inv);
            eb.y = f2bf(__sinf(base * (float)(q*4 + 2)) * inv);
            eb.z = f2bf(__sinf(base * (float)(q*4 + 3)) * inv);
            eb.w = f2bf(__sinf(base * (float)(q*4 + 4)) * inv);
            *(ushort4*)&epi_b[slot*40 + q*4] = eb;
            if (q == 0){
                ai_l[slot] = ia;
                pp_l[slot] = ip;
                float cw = (dist < CUTOFF_F) ? 0.5f * (__cosf(base) + 1.f) : 0.f;
                rc4_l[slot] = (float4){dx*inv, dy*inv, dz*inv, cw};
            }
        }
        __syncthreads();

        f32x4v pacc[2][4];
        #pragma unroll
        for (int mt = 0; mt < 2; mt++)
            #pragma unroll
            for (int nt = 0; nt < 4; nt++) pacc[mt][nt] = (f32x4v){0.f,0.f,0.f,0.f};
        #pragma unroll
        for (int mt = 0; mt < 2; mt++){
            const bf16x8 af = *(const bf16x8*)&epi_b[(mt*16 + lm)*40 + lq*8];
            #pragma unroll
            for (int nt = 0; nt < 4; nt++)
                pacc[mt][nt] = __builtin_amdgcn_mfma_f32_16x16x32_bf16(af, w1afr[nt], pacc[mt][nt], 0, 0, 0);
        }

        #pragma unroll
        for (int mt = 0; mt < 2; mt++){
            #pragma unroll
            for (int r = 0; r < 4; r++){
                const int e = mt*16 + lq*4 + r;
                const int i = ai_l[e];
                const float4 rc = rc4_l[e];
                const float* Tp = T + (size_t)i * F_DIM;
                const float* Up = U + (size_t)i * (3*F_DIM);
                #pragma unroll
                for (int nt = 0; nt < 4; nt++){
                    const int col = w*64 + nt*16 + lm;
                    float z = pacc[mt][nt][r] + Tp[col];
                    z = fmaf(rc.x, Up[col],           z);
                    z = fmaf(rc.y, Up[F_DIM + col],   z);
                    z = fmaf(rc.z, Up[2*F_DIM + col], z);
                    const int wofs = e*512 + ((col*2) ^ ((e & 7) << 4));
                    *(unsigned short*)(xbase + wofs) = f2bf(silu_f(z));
                }
            }
        }
        __syncthreads();

        f32x4v acc00 = {0.f,0.f,0.f,0.f}, acc01 = {0.f,0.f,0.f,0.f};
        f32x4v acc10 = {0.f,0.f,0.f,0.f}, acc11 = {0.f,0.f,0.f,0.f};
        const int eA0 = lm;
        const int eA1 = 16 + lm;
        #pragma unroll
        for (int kb = 0; kb < 8; kb++){
            const int ko = kb*64 + lq*16;
            bf16x8 af0 = *(const bf16x8*)(xbase + eA0*512 + (ko ^ ((eA0 & 7) << 4)));
            bf16x8 af1 = *(const bf16x8*)(xbase + eA1*512 + (ko ^ ((eA1 & 7) << 4)));
            acc00 = __builtin_amdgcn_mfma_f32_16x16x32_bf16(af0, bfr[0][kb], acc00, 0, 0, 0);
            acc01 = __builtin_amdgcn_mfma_f32_16x16x32_bf16(af0, bfr[1][kb], acc01, 0, 0, 0);
            acc10 = __builtin_amdgcn_mfma_f32_16x16x32_bf16(af1, bfr[0][kb], acc10, 0, 0, 0);
            acc11 = __builtin_amdgcn_mfma_f32_16x16x32_bf16(af1, bfr[1][kb], acc11, 0, 0, 0);
        }

        float pr0[4], pr1[4];
        #pragma unroll
        for (int r = 0; r < 4; r++){
            pr0[r] = silu_f(acc00[r] + b2v0) * w3v0 + silu_f(acc01[r] + b2v1) * w3v1;
            pr1[r] = silu_f(acc10[r] + b2v0) * w3v0 + silu_f(acc11[r] + b2v1) * w3v1;
        }
        #pragma unroll
        for (int r = 0; r < 4; r++){
            #pragma unroll
            for (int m = 8; m >= 1; m >>= 1){
                pr0[r] += __shfl_xor(pr0[r], m, 64);
                pr1[r] += __shfl_xor(pr1[r], m, 64);
            }
        }
        if (lm == 0){
            #pragma unroll
            for (int r = 0; r < 4; r++){
                part[w][lq*4 + r]      = pr0[r];
                part[w][16 + lq*4 + r] = pr1[r];
            }
        }
        __syncthreads();

        if (t < 32 && (e0b + t) < E){
            float tot = part[0][t] + part[1][t] + part[2][t] + part[3][t] + b3;
            atomicAdd(&rho[pp_l[t]], tot * rc4_l[t].w);
        }
        __syncthreads();
    }
}

extern "C" void kernel_launch(void* const* d_in, const int* in_sizes, int n_in,
                              void* d_out, int out_size, void* d_ws, size_t ws_size,
                              hipStream_t stream)
{
    const float* s_stack   = (const float*)d_in[0];
    const float* v_stack   = (const float*)d_in[1];
    const float* atom_xyz  = (const float*)d_in[2];
    const float* probe_xyz = (const float*)d_in[3];
    const float* cell      = (const float*)d_in[4];
    const float* disp      = (const float*)d_in[5];
    const float* attn_w1   = (const float*)d_in[6];
    const float* attn_b1   = (const float*)d_in[7];
    const float* attn_w2   = (const float*)d_in[8];
    const float* msg_w1    = (const float*)d_in[10];
    const float* msg_b1    = (const float*)d_in[11];
    const float* msg_w2    = (const float*)d_in[12];
    const float* msg_b2    = (const float*)d_in[13];
    const float* msg_w3    = (const float*)d_in[14];
    const float* msg_b3    = (const float*)d_in[15];
    const int*   pe        = (const int*)d_in[16];

    const int N = in_sizes[0] / (L_DIM * F_DIM);
    const int E = in_sizes[16] / 2;
    const int P = out_size;
    const size_t NF = (size_t)N * F_DIM;

    float* ws = (float*)d_ws;
    unsigned short* VJKb = (unsigned short*)ws;            // 3N x 256 bf16 (1.5 NF fl)
    unsigned short* NISb = VJKb + 3*NF;                    // N x 512 bf16  (1.0 NF fl)
    float* Ubuf = ws + (5*NF)/2;                           // 3N x 256 f32
    float* Tbuf = Ubuf + 3*NF;                             // N x 256 f32
    unsigned short* w1bt  = (unsigned short*)(Tbuf + NF);  // 256x256 bf16
    unsigned short* w1cdt = w1bt + 65536;                  // 256x512 bf16
    unsigned short* w2t   = w1cdt + 131072;                // 128x256 bf16
    unsigned short* wA1t  = w2t + 32768;                   // 128x256 bf16
    float* LG  = (float*)(wA1t + 32768);                   // 6N f32 logits
    int* cnt  = (int*)(LG + (size_t)N * L_DIM);
    int* pos  = cnt + N;
    int* offs = pos + N;
    int* perm = offs + N + 1;

    hipMemsetAsync(d_out, 0, (size_t)P * sizeof(float), stream);
    hipMemsetAsync(cnt, 0, 2 * (size_t)N * sizeof(int), stream);

    kPrep<<<1024, 256, 0, stream>>>(msg_w1, msg_w2, attn_w1, w1bt, w1cdt, w2t, wA1t);

    kL<<<(N * L_DIM) / 64, 256, 0, stream>>>(s_stack, wA1t, attn_b1, attn_w2, LG);
    kW<<<(N + 3) / 4, 256, 0, stream>>>(s_stack, v_stack, LG, VJKb, NISb, N);

    kA2u<<<(3 * N) / 128, 256, 0, stream>>>(VJKb, w1bt, Ubuf, 3 * N);
    kA2t<<<(N / 128) * 2, 256, 0, stream>>>(NISb, w1cdt, msg_b1, Tbuf, N);

    const int gE = (E + 255) / 256;
    kHist<<<gE, 256, 0, stream>>>(pe, cnt, E);
    kScan<<<1, 1024, 0, stream>>>(cnt, offs, N);
    kScatter<<<gE, 256, 0, stream>>>(pe, offs, pos, perm, E);

    kB1<<<(E + 127) / 128, 256, 0, stream>>>(pe, disp, cell, atom_xyz, probe_xyz,
                                             Ubuf, Tbuf, msg_w1,
                                             w2t, msg_b2, msg_w3, msg_b3,
                                             perm, (float*)d_out, E);
}

// Round 8
// 208.095 us; speedup vs baseline: 1.1701x; 1.0028x over previous
//
#include <hip/hip_runtime.h>
#include <math.h>
#include <stdint.h>

// PaiNN QM encoder, round 8.
//   U = V_JK @ W1b  (N,3,256)   T = b1 + n_i@W1c + S_JK@W1d  (N,256)
//   per edge: x = silu(T[i] + e_pi@W1a + r_hat.U[i]); m = (silu(x@W2+b2))@w3+b3
// r8 changes: U/T stored interleaved as UT4[n][col]={U0,U1,U2,T} so kB1's
// epilogue is ONE dwordx4 per (edge,col) pair (was 4 dwords); kB1 prefetches
// perm/pe metadata for all 4 batches at block entry. Rest verbatim from r7.

#define L_DIM 6
#define F_DIM 256
#define FH_DIM 128
#define DRBF 32
#define CUTOFF_F 4.0f
#define PI_F 3.14159265358979323846f

using bf16x8 = __attribute__((ext_vector_type(8))) short;
using f32x4v = __attribute__((ext_vector_type(4))) float;

__device__ __forceinline__ float silu_f(float x){ return x / (1.f + __expf(-x)); }

__device__ __forceinline__ unsigned short f2bf(float f){
    uint32_t u = __float_as_uint(f);
    uint32_t r = (u + 0x7fffu + ((u >> 16) & 1u)) >> 16;   // RNE
    return (unsigned short)r;
}

// ---------------- kPrep: transpose/convert weights to bf16 ----------------
__global__ __launch_bounds__(256) void kPrep(
    const float* __restrict__ msg_w1, const float* __restrict__ msg_w2,
    const float* __restrict__ attn_w1,
    unsigned short* __restrict__ w1bt, unsigned short* __restrict__ w1cdt,
    unsigned short* __restrict__ w2t, unsigned short* __restrict__ wA1t)
{
    int idx = blockIdx.x * 256 + threadIdx.x;
    if (idx < 65536){
        int k = idx >> 8, j = idx & 255;
        w1bt[(size_t)j * 256 + k] = f2bf(msg_w1[(size_t)(DRBF + k) * F_DIM + j]);
    } else if (idx < 196608){
        int i2 = idx - 65536;
        int k = i2 >> 8, j = i2 & 255;
        w1cdt[(size_t)j * 512 + k] = f2bf(msg_w1[(size_t)(DRBF + 256 + k) * F_DIM + j]);
    } else if (idx < 229376){
        int i3 = idx - 196608;
        int k = i3 >> 7, h = i3 & 127;
        w2t[(size_t)h * 256 + k] = f2bf(msg_w2[(size_t)k * FH_DIM + h]);
    } else {
        int i4 = idx - 229376;
        int j = i4 >> 8, k = i4 & 255;
        wA1t[(size_t)j * 256 + k] = f2bf(attn_w1[(size_t)k * FH_DIM + j]);
    }
}

// ---------------- kL: logits = (silu(s2d @ W1 + b1)).w2  (MFMA, validated r7) ----------------
__global__ __launch_bounds__(256) void kL(
    const float* __restrict__ s2d, const unsigned short* __restrict__ wA1t,
    const float* __restrict__ attn_b1, const float* __restrict__ attn_w2,
    float* __restrict__ LG)
{
    __shared__ float part[4][64];

    const int t  = threadIdx.x;
    const int l  = t & 63;
    const int w  = t >> 6;
    const int lm = l & 15, lq = l >> 4;

    bf16x8 bfr[2][8];
    #pragma unroll
    for (int nt2 = 0; nt2 < 2; nt2++){
        const int col = w*32 + nt2*16 + lm;
        #pragma unroll
        for (int kb = 0; kb < 8; kb++)
            bfr[nt2][kb] = *(const bf16x8*)(wA1t + (size_t)col * 256 + kb*32 + lq*8);
    }
    const float b1a = attn_b1[w*32 + lm];
    const float b1b = attn_b1[w*32 + 16 + lm];
    const float w2a = attn_w2[w*32 + lm];
    const float w2b = attn_w2[w*32 + 16 + lm];

    const int r00 = blockIdx.x * 64;

    #pragma unroll
    for (int mt = 0; mt < 4; mt++){
        const int r0 = r00 + mt * 16;
        bf16x8 af[8];
        #pragma unroll
        for (int kb = 0; kb < 8; kb++){
            const float* ap = s2d + (size_t)(r0 + lm) * 256 + kb*32 + lq*8;
            float4 fa = *(const float4*)ap;
            float4 fb = *(const float4*)(ap + 4);
            bf16x8 v;
            v[0] = (short)f2bf(fa.x); v[1] = (short)f2bf(fa.y);
            v[2] = (short)f2bf(fa.z); v[3] = (short)f2bf(fa.w);
            v[4] = (short)f2bf(fb.x); v[5] = (short)f2bf(fb.y);
            v[6] = (short)f2bf(fb.z); v[7] = (short)f2bf(fb.w);
            af[kb] = v;
        }
        f32x4v a0 = {0.f,0.f,0.f,0.f}, a1 = {0.f,0.f,0.f,0.f};
        #pragma unroll
        for (int kb = 0; kb < 8; kb++){
            a0 = __builtin_amdgcn_mfma_f32_16x16x32_bf16(af[kb], bfr[0][kb], a0, 0, 0, 0);
            a1 = __builtin_amdgcn_mfma_f32_16x16x32_bf16(af[kb], bfr[1][kb], a1, 0, 0, 0);
        }
        #pragma unroll
        for (int r = 0; r < 4; r++){
            float p = silu_f(a0[r] + b1a) * w2a + silu_f(a1[r] + b1b) * w2b;
            #pragma unroll
            for (int m = 8; m >= 1; m >>= 1) p += __shfl_xor(p, m, 64);
            if (lm == 0) part[w][mt*16 + lq*4 + r] = p;
        }
    }
    __syncthreads();
    if (t < 64)
        LG[r00 + t] = part[0][t] + part[1][t] + part[2][t] + part[3][t];
}

// ---------------- kW: wave-per-atom softmax + weighted-sum stream (validated r7) ----------------
__global__ __launch_bounds__(256) void kW(
    const float* __restrict__ s_stack, const float* __restrict__ v_stack,
    const float* __restrict__ LG,
    unsigned short* __restrict__ VJKb, unsigned short* __restrict__ NISb, int N)
{
    const int t    = threadIdx.x;
    const int w    = t >> 6;
    const int lane = t & 63;
    const int n    = min(blockIdx.x * 4 + w, N - 1);

    float aw[L_DIM];
    #pragma unroll
    for (int l = 0; l < L_DIM; l++) aw[l] = LG[(size_t)n * L_DIM + l];
    float mx = aw[0];
    #pragma unroll
    for (int l = 1; l < L_DIM; l++) mx = fmaxf(mx, aw[l]);
    float sum = 0.f;
    #pragma unroll
    for (int l = 0; l < L_DIM; l++){ aw[l] = __expf(aw[l] - mx); sum += aw[l]; }
    const float inv = 1.f / sum;
    #pragma unroll
    for (int l = 0; l < L_DIM; l++) aw[l] *= inv;

    const float* sp = s_stack + (size_t)n * (L_DIM * F_DIM) + lane * 4;
    const float* vp = v_stack + (size_t)n * (L_DIM * 3 * F_DIM) + lane * 4;
    float4 v0 = {0.f,0.f,0.f,0.f}, v1 = {0.f,0.f,0.f,0.f}, v2 = {0.f,0.f,0.f,0.f};
    float4 sj = {0.f,0.f,0.f,0.f};
    #pragma unroll
    for (int l = 0; l < L_DIM; l++){
        const float a = aw[l];
        float4 ss = *(const float4*)(sp + (size_t)l * F_DIM);
        float4 x0 = *(const float4*)(vp + (size_t)(l*3+0) * F_DIM);
        float4 x1 = *(const float4*)(vp + (size_t)(l*3+1) * F_DIM);
        float4 x2 = *(const float4*)(vp + (size_t)(l*3+2) * F_DIM);
        v0.x = fmaf(a, x0.x, v0.x); v0.y = fmaf(a, x0.y, v0.y);
        v0.z = fmaf(a, x0.z, v0.z); v0.w = fmaf(a, x0.w, v0.w);
        v1.x = fmaf(a, x1.x, v1.x); v1.y = fmaf(a, x1.y, v1.y);
        v1.z = fmaf(a, x1.z, v1.z); v1.w = fmaf(a, x1.w, v1.w);
        v2.x = fmaf(a, x2.x, v2.x); v2.y = fmaf(a, x2.y, v2.y);
        v2.z = fmaf(a, x2.z, v2.z); v2.w = fmaf(a, x2.w, v2.w);
        sj.x = fmaf(a, ss.x, sj.x); sj.y = fmaf(a, ss.y, sj.y);
        sj.z = fmaf(a, ss.z, sj.z); sj.w = fmaf(a, ss.w, sj.w);
    }
    float4 ni;
    ni.x = sqrtf(v0.x*v0.x + v1.x*v1.x + v2.x*v2.x);
    ni.y = sqrtf(v0.y*v0.y + v1.y*v1.y + v2.y*v2.y);
    ni.z = sqrtf(v0.z*v0.z + v1.z*v1.z + v2.z*v2.z);
    ni.w = sqrtf(v0.w*v0.w + v1.w*v1.w + v2.w*v2.w);

    ushort4 o;
    o = (ushort4){f2bf(v0.x), f2bf(v0.y), f2bf(v0.z), f2bf(v0.w)};
    *(ushort4*)&VJKb[((size_t)n*3 + 0) * F_DIM + lane*4] = o;
    o = (ushort4){f2bf(v1.x), f2bf(v1.y), f2bf(v1.z), f2bf(v1.w)};
    *(ushort4*)&VJKb[((size_t)n*3 + 1) * F_DIM + lane*4] = o;
    o = (ushort4){f2bf(v2.x), f2bf(v2.y), f2bf(v2.z), f2bf(v2.w)};
    *(ushort4*)&VJKb[((size_t)n*3 + 2) * F_DIM + lane*4] = o;
    o = (ushort4){f2bf(ni.x), f2bf(ni.y), f2bf(ni.z), f2bf(ni.w)};
    *(ushort4*)&NISb[(size_t)n * 512 + lane*4] = o;
    o = (ushort4){f2bf(sj.x), f2bf(sj.y), f2bf(sj.z), f2bf(sj.w)};
    *(ushort4*)&NISb[(size_t)n * 512 + 256 + lane*4] = o;
}

// ---------------- kA2u: U rows -> UT4 components 0..2 (MFMA core validated r4-r7) ----------------
__global__ __launch_bounds__(256) void kA2u(
    const unsigned short* __restrict__ VJKb, const unsigned short* __restrict__ w1bt,
    float* __restrict__ UT4, int M)
{
    const int t  = threadIdx.x;
    const int l  = t & 63;
    const int w  = t >> 6;
    const int lm = l & 15, lq = l >> 4;

    bf16x8 bfr[4][8];
    #pragma unroll
    for (int ct = 0; ct < 4; ct++)
        #pragma unroll
        for (int kb = 0; kb < 8; kb++)
            bfr[ct][kb] = *(const bf16x8*)(w1bt + (size_t)(w*64 + ct*16 + lm) * 256 + kb*32 + lq*8);

    const int r00 = blockIdx.x * 128;
    #pragma unroll 1
    for (int mt = 0; mt < 8; mt++){
        const int r0 = r00 + mt * 16;
        bf16x8 af[8];
        #pragma unroll
        for (int kb = 0; kb < 8; kb++)
            af[kb] = *(const bf16x8*)(VJKb + (size_t)(r0 + lm) * 256 + kb*32 + lq*8);
        f32x4v acc[4];
        #pragma unroll
        for (int ct = 0; ct < 4; ct++) acc[ct] = (f32x4v){0.f,0.f,0.f,0.f};
        #pragma unroll
        for (int kb = 0; kb < 8; kb++)
            #pragma unroll
            for (int ct = 0; ct < 4; ct++)
                acc[ct] = __builtin_amdgcn_mfma_f32_16x16x32_bf16(af[kb], bfr[ct][kb], acc[ct], 0, 0, 0);
        #pragma unroll
        for (int ct = 0; ct < 4; ct++){
            const int col = w*64 + ct*16 + lm;
            #pragma unroll
            for (int r = 0; r < 4; r++){
                const int row = r0 + lq*4 + r;     // row of (3N,256) U
                const int n = row / 3, c = row - n*3;
                UT4[(((size_t)n << 8) + col) * 4 + c] = acc[ct][r];
            }
        }
    }
}

// ---------------- kA2t: T -> UT4 component 3 (MFMA core validated r4-r7) ----------------
__global__ __launch_bounds__(256) void kA2t(
    const unsigned short* __restrict__ NISb, const unsigned short* __restrict__ w1cdt,
    const float* __restrict__ msg_b1,
    float* __restrict__ UT4, int M)
{
    const int t  = threadIdx.x;
    const int l  = t & 63;
    const int w  = t >> 6;
    const int lm = l & 15, lq = l >> 4;

    const int ch = blockIdx.x & 1;
    const int bm = blockIdx.x >> 1;

    bf16x8 bfr[2][16];
    #pragma unroll
    for (int ct = 0; ct < 2; ct++)
        #pragma unroll
        for (int kb = 0; kb < 16; kb++)
            bfr[ct][kb] = *(const bf16x8*)(w1cdt + (size_t)(ch*128 + w*32 + ct*16 + lm) * 512 + kb*32 + lq*8);

    const int r00 = bm * 128;
    #pragma unroll 1
    for (int mt = 0; mt < 8; mt++){
        const int r0 = r00 + mt * 16;
        bf16x8 af[16];
        #pragma unroll
        for (int kb = 0; kb < 16; kb++)
            af[kb] = *(const bf16x8*)(NISb + (size_t)(r0 + lm) * 512 + kb*32 + lq*8);
        f32x4v acc[2];
        #pragma unroll
        for (int ct = 0; ct < 2; ct++) acc[ct] = (f32x4v){0.f,0.f,0.f,0.f};
        #pragma unroll
        for (int kb = 0; kb < 16; kb++)
            #pragma unroll
            for (int ct = 0; ct < 2; ct++)
                acc[ct] = __builtin_amdgcn_mfma_f32_16x16x32_bf16(af[kb], bfr[ct][kb], acc[ct], 0, 0, 0);
        #pragma unroll
        for (int ct = 0; ct < 2; ct++){
            const int col = ch*128 + w*32 + ct*16 + lm;
            const float bias = msg_b1[col];
            #pragma unroll
            for (int r = 0; r < 4; r++){
                const int n = r0 + lq*4 + r;
                UT4[(((size_t)n << 8) + col) * 4 + 3] = acc[ct][r] + bias;
            }
        }
    }
}

// ---------------- CSR binning ----------------
__global__ __launch_bounds__(256) void kHist(const int* __restrict__ pe, int* __restrict__ cnt, int E){
    int e = blockIdx.x * 256 + threadIdx.x;
    if (e < E) atomicAdd(&cnt[pe[(size_t)e*2]], 1);
}

__global__ __launch_bounds__(1024) void kScan(const int* __restrict__ cnt, int* __restrict__ off, int N){
    __shared__ int sums[1024];
    const int t = threadIdx.x;
    const int base = t * 8;
    int c[8]; int s = 0;
    #pragma unroll
    for (int j = 0; j < 8; j++){
        int v = (base + j < N) ? cnt[base + j] : 0;
        c[j] = s; s += v;
    }
    sums[t] = s;
    __syncthreads();
    for (int d = 1; d < 1024; d <<= 1){
        int v = (t >= d) ? sums[t - d] : 0;
        __syncthreads();
        sums[t] += v;
        __syncthreads();
    }
    int excl = (t == 0) ? 0 : sums[t - 1];
    #pragma unroll
    for (int j = 0; j < 8; j++)
        if (base + j < N) off[base + j] = excl + c[j];
    if (t == 1023) off[N] = sums[1023];
}

__global__ __launch_bounds__(256) void kScatter(const int* __restrict__ pe,
    const int* __restrict__ off, int* __restrict__ pos, int* __restrict__ perm, int E){
    int e = blockIdx.x * 256 + threadIdx.x;
    if (e < E){
        int i = pe[(size_t)e*2];
        int slot = atomicAdd(&pos[i], 1);
        perm[off[i] + slot] = e;
    }
}

// ---------------- kB1: fused geometry + edge MLP + scatter ----------------
// r8: UT4 float4 epilogue loads; perm/pe prefetched for all 4 batches.
__global__ __launch_bounds__(256) void kB1(
    const int* __restrict__ pe, const float* __restrict__ disp,
    const float* __restrict__ cell,
    const float* __restrict__ atom_xyz, const float* __restrict__ probe_xyz,
    const float* __restrict__ UT4,
    const float* __restrict__ msg_w1,
    const unsigned short* __restrict__ w2t, const float* __restrict__ msg_b2,
    const float* __restrict__ msg_w3, const float* __restrict__ msg_b3,
    const int* __restrict__ perm,
    float* __restrict__ rho, int E)
{
    __shared__ unsigned short x_lds[32 * 256];   // 16 KB, XOR-swizzled
    __shared__ unsigned short epi_b[32 * 40];    // 2.5 KB, bf16 A-tile (pad 40)
    __shared__ int   ai_l[32];
    __shared__ int   pp_l[32];
    __shared__ float4 rc4_l[32];
    __shared__ float part[4][32];

    char* xbase = (char*)x_lds;

    const int t  = threadIdx.x;
    const int l  = t & 63;
    const int w  = t >> 6;
    const int lq = l >> 4;
    const int lm = l & 15;

    const float c0 = cell[0], c1 = cell[1], c2 = cell[2];
    const float c3 = cell[3], c4 = cell[4], c5 = cell[5];
    const float c6 = cell[6], c7 = cell[7], c8 = cell[8];

    bf16x8 w1afr[4];
    #pragma unroll
    for (int nt = 0; nt < 4; nt++){
        const int col = w*64 + nt*16 + lm;
        bf16x8 v;
        #pragma unroll
        for (int j = 0; j < 8; j++)
            v[j] = (short)f2bf(msg_w1[(size_t)(lq*8 + j) * F_DIM + col]);
        w1afr[nt] = v;
    }

    bf16x8 bfr[2][8];
    #pragma unroll
    for (int nt2 = 0; nt2 < 2; nt2++){
        const int h = w*32 + nt2*16 + lm;
        #pragma unroll
        for (int kb = 0; kb < 8; kb++)
            bfr[nt2][kb] = *(const bf16x8*)(w2t + (size_t)h * F_DIM + kb*32 + lq*8);
    }
    const float b2v0 = msg_b2[w*32 + lm];
    const float b2v1 = msg_b2[w*32 + 16 + lm];
    const float w3v0 = msg_w3[w*32 + lm];
    const float w3v1 = msg_w3[w*32 + 16 + lm];
    const float b3   = msg_b3[0];

    const int e0 = blockIdx.x * 128;

    // prefetch per-batch edge metadata (slot = t>>3 for each batch)
    int ee_r[4], ia_r[4], ip_r[4];
    #pragma unroll
    for (int bb = 0; bb < 4; bb++){
        int s = min(e0 + bb*32 + (t >> 3), E - 1);
        ee_r[bb] = perm[s];
    }
    #pragma unroll
    for (int bb = 0; bb < 4; bb++){
        ia_r[bb] = pe[(size_t)ee_r[bb]*2];
        ip_r[bb] = pe[(size_t)ee_r[bb]*2 + 1];
    }

    #pragma unroll 1
    for (int bb = 0; bb < 4; bb++){
        const int e0b = e0 + bb * 32;

        {
            const int slot = t >> 3, q = t & 7;
            const int ee = ee_r[bb];
            const int ia = ia_r[bb];
            const int ip = ip_r[bb];
            const float d0 = disp[(size_t)ee*3], d1 = disp[(size_t)ee*3+1], d2 = disp[(size_t)ee*3+2];
            const float sx = d0*c0 + d1*c3 + d2*c6;
            const float sy = d0*c1 + d1*c4 + d2*c7;
            const float sz = d0*c2 + d1*c5 + d2*c8;
            const float dx = probe_xyz[(size_t)ip*3+0] - (atom_xyz[(size_t)ia*3+0] + sx);
            const float dy = probe_xyz[(size_t)ip*3+1] - (atom_xyz[(size_t)ia*3+1] + sy);
            const float dz = probe_xyz[(size_t)ip*3+2] - (atom_xyz[(size_t)ia*3+2] + sz);
            const float dist = sqrtf(dx*dx + dy*dy + dz*dz);
            const float inv  = 1.f / (dist + 1e-8f);
            const float base = dist * (PI_F / CUTOFF_F);
            ushort4 eb;
            eb.x = f2bf(__sinf(base * (float)(q*4 + 1)) * inv);
            eb.y = f2bf(__sinf(base * (float)(q*4 + 2)) * inv);
            eb.z = f2bf(__sinf(base * (float)(q*4 + 3)) * inv);
            eb.w = f2bf(__sinf(base * (float)(q*4 + 4)) * inv);
            *(ushort4*)&epi_b[slot*40 + q*4] = eb;
            if (q == 0){
                ai_l[slot] = ia;
                pp_l[slot] = ip;
                float cw = (dist < CUTOFF_F) ? 0.5f * (__cosf(base) + 1.f) : 0.f;
                rc4_l[slot] = (float4){dx*inv, dy*inv, dz*inv, cw};
            }
        }
        __syncthreads();

        f32x4v pacc[2][4];
        #pragma unroll
        for (int mt = 0; mt < 2; mt++)
            #pragma unroll
            for (int nt = 0; nt < 4; nt++) pacc[mt][nt] = (f32x4v){0.f,0.f,0.f,0.f};
        #pragma unroll
        for (int mt = 0; mt < 2; mt++){
            const bf16x8 af = *(const bf16x8*)&epi_b[(mt*16 + lm)*40 + lq*8];
            #pragma unroll
            for (int nt = 0; nt < 4; nt++)
                pacc[mt][nt] = __builtin_amdgcn_mfma_f32_16x16x32_bf16(af, w1afr[nt], pacc[mt][nt], 0, 0, 0);
        }

        #pragma unroll
        for (int mt = 0; mt < 2; mt++){
            #pragma unroll
            for (int r = 0; r < 4; r++){
                const int e = mt*16 + lq*4 + r;
                const int i = ai_l[e];
                const float4 rc = rc4_l[e];
                const float* up = UT4 + ((size_t)i << 10);
                #pragma unroll
                for (int nt = 0; nt < 4; nt++){
                    const int col = w*64 + nt*16 + lm;
                    const float4 ut = *(const float4*)(up + (size_t)col * 4);
                    float z = pacc[mt][nt][r] + ut.w;
                    z = fmaf(rc.x, ut.x, fmaf(rc.y, ut.y, fmaf(rc.z, ut.z, z)));
                    const int wofs = e*512 + ((col*2) ^ ((e & 7) << 4));
                    *(unsigned short*)(xbase + wofs) = f2bf(silu_f(z));
                }
            }
        }
        __syncthreads();

        f32x4v acc00 = {0.f,0.f,0.f,0.f}, acc01 = {0.f,0.f,0.f,0.f};
        f32x4v acc10 = {0.f,0.f,0.f,0.f}, acc11 = {0.f,0.f,0.f,0.f};
        const int eA0 = lm;
        const int eA1 = 16 + lm;
        #pragma unroll
        for (int kb = 0; kb < 8; kb++){
            const int ko = kb*64 + lq*16;
            bf16x8 af0 = *(const bf16x8*)(xbase + eA0*512 + (ko ^ ((eA0 & 7) << 4)));
            bf16x8 af1 = *(const bf16x8*)(xbase + eA1*512 + (ko ^ ((eA1 & 7) << 4)));
            acc00 = __builtin_amdgcn_mfma_f32_16x16x32_bf16(af0, bfr[0][kb], acc00, 0, 0, 0);
            acc01 = __builtin_amdgcn_mfma_f32_16x16x32_bf16(af0, bfr[1][kb], acc01, 0, 0, 0);
            acc10 = __builtin_amdgcn_mfma_f32_16x16x32_bf16(af1, bfr[0][kb], acc10, 0, 0, 0);
            acc11 = __builtin_amdgcn_mfma_f32_16x16x32_bf16(af1, bfr[1][kb], acc11, 0, 0, 0);
        }

        float pr0[4], pr1[4];
        #pragma unroll
        for (int r = 0; r < 4; r++){
            pr0[r] = silu_f(acc00[r] + b2v0) * w3v0 + silu_f(acc01[r] + b2v1) * w3v1;
            pr1[r] = silu_f(acc10[r] + b2v0) * w3v0 + silu_f(acc11[r] + b2v1) * w3v1;
        }
        #pragma unroll
        for (int r = 0; r < 4; r++){
            #pragma unroll
            for (int m = 8; m >= 1; m >>= 1){
                pr0[r] += __shfl_xor(pr0[r], m, 64);
                pr1[r] += __shfl_xor(pr1[r], m, 64);
            }
        }
        if (lm == 0){
            #pragma unroll
            for (int r = 0; r < 4; r++){
                part[w][lq*4 + r]      = pr0[r];
                part[w][16 + lq*4 + r] = pr1[r];
            }
        }
        __syncthreads();

        if (t < 32 && (e0b + t) < E){
            float tot = part[0][t] + part[1][t] + part[2][t] + part[3][t] + b3;
            atomicAdd(&rho[pp_l[t]], tot * rc4_l[t].w);
        }
        __syncthreads();
    }
}

extern "C" void kernel_launch(void* const* d_in, const int* in_sizes, int n_in,
                              void* d_out, int out_size, void* d_ws, size_t ws_size,
                              hipStream_t stream)
{
    const float* s_stack   = (const float*)d_in[0];
    const float* v_stack   = (const float*)d_in[1];
    const float* atom_xyz  = (const float*)d_in[2];
    const float* probe_xyz = (const float*)d_in[3];
    const float* cell      = (const float*)d_in[4];
    const float* disp      = (const float*)d_in[5];
    const float* attn_w1   = (const float*)d_in[6];
    const float* attn_b1   = (const float*)d_in[7];
    const float* attn_w2   = (const float*)d_in[8];
    const float* msg_w1    = (const float*)d_in[10];
    const float* msg_b1    = (const float*)d_in[11];
    const float* msg_w2    = (const float*)d_in[12];
    const float* msg_b2    = (const float*)d_in[13];
    const float* msg_w3    = (const float*)d_in[14];
    const float* msg_b3    = (const float*)d_in[15];
    const int*   pe        = (const int*)d_in[16];

    const int N = in_sizes[0] / (L_DIM * F_DIM);
    const int E = in_sizes[16] / 2;
    const int P = out_size;
    const size_t NF = (size_t)N * F_DIM;

    float* ws = (float*)d_ws;
    unsigned short* VJKb = (unsigned short*)ws;            // 3N x 256 bf16 (1.5 NF fl)
    unsigned short* NISb = VJKb + 3*NF;                    // N x 512 bf16  (1.0 NF fl)
    float* UT4 = ws + (5*NF)/2;                            // N x 256 x 4 f32 (4 NF fl)
    unsigned short* w1bt  = (unsigned short*)(ws + (13*NF)/2);  // 256x256 bf16
    unsigned short* w1cdt = w1bt + 65536;                  // 256x512 bf16
    unsigned short* w2t   = w1cdt + 131072;                // 128x256 bf16
    unsigned short* wA1t  = w2t + 32768;                   // 128x256 bf16
    float* LG  = (float*)(wA1t + 32768);                   // 6N f32 logits
    int* cnt  = (int*)(LG + (size_t)N * L_DIM);
    int* pos  = cnt + N;
    int* offs = pos + N;
    int* perm = offs + N + 1;

    hipMemsetAsync(d_out, 0, (size_t)P * sizeof(float), stream);
    hipMemsetAsync(cnt, 0, 2 * (size_t)N * sizeof(int), stream);

    kPrep<<<1024, 256, 0, stream>>>(msg_w1, msg_w2, attn_w1, w1bt, w1cdt, w2t, wA1t);

    kL<<<(N * L_DIM) / 64, 256, 0, stream>>>(s_stack, wA1t, attn_b1, attn_w2, LG);
    kW<<<(N + 3) / 4, 256, 0, stream>>>(s_stack, v_stack, LG, VJKb, NISb, N);

    kA2u<<<(3 * N) / 128, 256, 0, stream>>>(VJKb, w1bt, UT4, 3 * N);
    kA2t<<<(N / 128) * 2, 256, 0, stream>>>(NISb, w1cdt, msg_b1, UT4, N);

    const int gE = (E + 255) / 256;
    kHist<<<gE, 256, 0, stream>>>(pe, cnt, E);
    kScan<<<1, 1024, 0, stream>>>(cnt, offs, N);
    kScatter<<<gE, 256, 0, stream>>>(pe, offs, pos, perm, E);

    kB1<<<(E + 127) / 128, 256, 0, stream>>>(pe, disp, cell, atom_xyz, probe_xyz,
                                             UT4, msg_w1,
                                             w2t, msg_b2, msg_w3, msg_b3,
                                             perm, (float*)d_out, E);
}

// Round 9
// 204.473 us; speedup vs baseline: 1.1908x; 1.0177x over previous
//
#include <hip/hip_runtime.h>
#include <math.h>
#include <stdint.h>

// PaiNN QM encoder, round 9.
//   U = V_JK @ W1b  (N,3,256)   T = b1 + n_i@W1c + S_JK@W1d  (N,256)
//   per edge: x = silu(T[i] + e_pi@W1a + r_hat.U[i]); m = (silu(x@W2+b2))@w3+b3
// r9: kAW fuses kL (MFMA logits, validated r7/r8) + kW (v-stream, validated
// r6-r8) into one kernel (one s pass). kB1 moves to 64-edge super-batches:
// 3 barriers per 64 edges (was 8), double-buffered epi/meta, geometry
// prefetched into registers during the previous batch's compute.

#define L_DIM 6
#define F_DIM 256
#define FH_DIM 128
#define DRBF 32
#define CUTOFF_F 4.0f
#define PI_F 3.14159265358979323846f

using bf16x8 = __attribute__((ext_vector_type(8))) short;
using f32x4v = __attribute__((ext_vector_type(4))) float;

__device__ __forceinline__ float silu_f(float x){ return x / (1.f + __expf(-x)); }

__device__ __forceinline__ unsigned short f2bf(float f){
    uint32_t u = __float_as_uint(f);
    uint32_t r = (u + 0x7fffu + ((u >> 16) & 1u)) >> 16;   // RNE
    return (unsigned short)r;
}

// ---------------- kPrep: transpose/convert weights to bf16 ----------------
__global__ __launch_bounds__(256) void kPrep(
    const float* __restrict__ msg_w1, const float* __restrict__ msg_w2,
    const float* __restrict__ attn_w1,
    unsigned short* __restrict__ w1bt, unsigned short* __restrict__ w1cdt,
    unsigned short* __restrict__ w2t, unsigned short* __restrict__ wA1t)
{
    int idx = blockIdx.x * 256 + threadIdx.x;
    if (idx < 65536){
        int k = idx >> 8, j = idx & 255;
        w1bt[(size_t)j * 256 + k] = f2bf(msg_w1[(size_t)(DRBF + k) * F_DIM + j]);
    } else if (idx < 196608){
        int i2 = idx - 65536;
        int k = i2 >> 8, j = i2 & 255;
        w1cdt[(size_t)j * 512 + k] = f2bf(msg_w1[(size_t)(DRBF + 256 + k) * F_DIM + j]);
    } else if (idx < 229376){
        int i3 = idx - 196608;
        int k = i3 >> 7, h = i3 & 127;
        w2t[(size_t)h * 256 + k] = f2bf(msg_w2[(size_t)k * FH_DIM + h]);
    } else {
        int i4 = idx - 229376;
        int j = i4 >> 8, k = i4 & 255;
        wA1t[(size_t)j * 256 + k] = f2bf(attn_w1[(size_t)k * FH_DIM + j]);
    }
}

// ---------------- kAW: fused attention (MFMA logits + softmax + v-stream) ----------------
// Block = 16 atoms = 96 rows of s2d. Phase 1: kL's validated MFMA logits path
// (6 m-tiles). Phase 2: kW's validated float4 weighted-sum stream.
__global__ __launch_bounds__(256) void kAW(
    const float* __restrict__ s_stack, const float* __restrict__ v_stack,
    const unsigned short* __restrict__ wA1t,
    const float* __restrict__ attn_b1, const float* __restrict__ attn_w2,
    unsigned short* __restrict__ VJKb, unsigned short* __restrict__ NISb, int N)
{
    __shared__ float part[4][96];
    __shared__ float aw_l[16][8];

    const int t  = threadIdx.x;
    const int l  = t & 63;
    const int w  = t >> 6;
    const int lm = l & 15, lq = l >> 4;

    bf16x8 bfr[2][8];
    #pragma unroll
    for (int nt2 = 0; nt2 < 2; nt2++){
        const int col = w*32 + nt2*16 + lm;
        #pragma unroll
        for (int kb = 0; kb < 8; kb++)
            bfr[nt2][kb] = *(const bf16x8*)(wA1t + (size_t)col * 256 + kb*32 + lq*8);
    }
    const float b1a = attn_b1[w*32 + lm];
    const float b1b = attn_b1[w*32 + 16 + lm];
    const float w2a = attn_w2[w*32 + lm];
    const float w2b = attn_w2[w*32 + 16 + lm];

    const int n0 = blockIdx.x * 16;
    const size_t rbase = (size_t)n0 * L_DIM;
    const size_t rmax  = (size_t)N * L_DIM - 1;

    // ---- phase 1: logits ----
    #pragma unroll
    for (int mt = 0; mt < 6; mt++){
        const size_t r0 = rbase + mt * 16;
        bf16x8 af[8];
        #pragma unroll
        for (int kb = 0; kb < 8; kb++){
            size_t row = r0 + lm; if (row > rmax) row = rmax;
            const float* ap = s_stack + row * 256 + kb*32 + lq*8;
            float4 fa = *(const float4*)ap;
            float4 fb = *(const float4*)(ap + 4);
            bf16x8 v;
            v[0] = (short)f2bf(fa.x); v[1] = (short)f2bf(fa.y);
            v[2] = (short)f2bf(fa.z); v[3] = (short)f2bf(fa.w);
            v[4] = (short)f2bf(fb.x); v[5] = (short)f2bf(fb.y);
            v[6] = (short)f2bf(fb.z); v[7] = (short)f2bf(fb.w);
            af[kb] = v;
        }
        f32x4v a0 = {0.f,0.f,0.f,0.f}, a1 = {0.f,0.f,0.f,0.f};
        #pragma unroll
        for (int kb = 0; kb < 8; kb++){
            a0 = __builtin_amdgcn_mfma_f32_16x16x32_bf16(af[kb], bfr[0][kb], a0, 0, 0, 0);
            a1 = __builtin_amdgcn_mfma_f32_16x16x32_bf16(af[kb], bfr[1][kb], a1, 0, 0, 0);
        }
        #pragma unroll
        for (int r = 0; r < 4; r++){
            float p = silu_f(a0[r] + b1a) * w2a + silu_f(a1[r] + b1b) * w2b;
            #pragma unroll
            for (int m = 8; m >= 1; m >>= 1) p += __shfl_xor(p, m, 64);
            if (lm == 0) part[w][mt*16 + lq*4 + r] = p;
        }
    }
    __syncthreads();
    if (t < 96) part[0][t] = part[0][t] + part[1][t] + part[2][t] + part[3][t];
    __syncthreads();
    if (t < 16){
        float e[L_DIM]; float mx = -1e30f;
        #pragma unroll
        for (int l6 = 0; l6 < L_DIM; l6++) mx = fmaxf(mx, part[0][t*L_DIM + l6]);
        float s = 0.f;
        #pragma unroll
        for (int l6 = 0; l6 < L_DIM; l6++){ e[l6] = __expf(part[0][t*L_DIM + l6] - mx); s += e[l6]; }
        float inv = 1.f / s;
        #pragma unroll
        for (int l6 = 0; l6 < L_DIM; l6++) aw_l[t][l6] = e[l6] * inv;
    }
    __syncthreads();

    // ---- phase 2: weighted sums (wave handles 4 atoms) ----
    #pragma unroll 1
    for (int aa = 0; aa < 4; aa++){
        const int n = min(n0 + w*4 + aa, N - 1);
        float aw[L_DIM];
        #pragma unroll
        for (int l6 = 0; l6 < L_DIM; l6++) aw[l6] = aw_l[w*4 + aa][l6];

        const float* sp = s_stack + (size_t)n * (L_DIM * F_DIM) + l * 4;
        const float* vp = v_stack + (size_t)n * (L_DIM * 3 * F_DIM) + l * 4;
        float4 v0 = {0.f,0.f,0.f,0.f}, v1 = {0.f,0.f,0.f,0.f}, v2 = {0.f,0.f,0.f,0.f};
        float4 sj = {0.f,0.f,0.f,0.f};
        #pragma unroll
        for (int l6 = 0; l6 < L_DIM; l6++){
            const float a = aw[l6];
            float4 ss = *(const float4*)(sp + (size_t)l6 * F_DIM);
            float4 x0 = *(const float4*)(vp + (size_t)(l6*3+0) * F_DIM);
            float4 x1 = *(const float4*)(vp + (size_t)(l6*3+1) * F_DIM);
            float4 x2 = *(const float4*)(vp + (size_t)(l6*3+2) * F_DIM);
            v0.x = fmaf(a, x0.x, v0.x); v0.y = fmaf(a, x0.y, v0.y);
            v0.z = fmaf(a, x0.z, v0.z); v0.w = fmaf(a, x0.w, v0.w);
            v1.x = fmaf(a, x1.x, v1.x); v1.y = fmaf(a, x1.y, v1.y);
            v1.z = fmaf(a, x1.z, v1.z); v1.w = fmaf(a, x1.w, v1.w);
            v2.x = fmaf(a, x2.x, v2.x); v2.y = fmaf(a, x2.y, v2.y);
            v2.z = fmaf(a, x2.z, v2.z); v2.w = fmaf(a, x2.w, v2.w);
            sj.x = fmaf(a, ss.x, sj.x); sj.y = fmaf(a, ss.y, sj.y);
            sj.z = fmaf(a, ss.z, sj.z); sj.w = fmaf(a, ss.w, sj.w);
        }
        float4 ni;
        ni.x = sqrtf(v0.x*v0.x + v1.x*v1.x + v2.x*v2.x);
        ni.y = sqrtf(v0.y*v0.y + v1.y*v1.y + v2.y*v2.y);
        ni.z = sqrtf(v0.z*v0.z + v1.z*v1.z + v2.z*v2.z);
        ni.w = sqrtf(v0.w*v0.w + v1.w*v1.w + v2.w*v2.w);

        ushort4 o;
        o = (ushort4){f2bf(v0.x), f2bf(v0.y), f2bf(v0.z), f2bf(v0.w)};
        *(ushort4*)&VJKb[((size_t)n*3 + 0) * F_DIM + l*4] = o;
        o = (ushort4){f2bf(v1.x), f2bf(v1.y), f2bf(v1.z), f2bf(v1.w)};
        *(ushort4*)&VJKb[((size_t)n*3 + 1) * F_DIM + l*4] = o;
        o = (ushort4){f2bf(v2.x), f2bf(v2.y), f2bf(v2.z), f2bf(v2.w)};
        *(ushort4*)&VJKb[((size_t)n*3 + 2) * F_DIM + l*4] = o;
        o = (ushort4){f2bf(ni.x), f2bf(ni.y), f2bf(ni.z), f2bf(ni.w)};
        *(ushort4*)&NISb[(size_t)n * 512 + l*4] = o;
        o = (ushort4){f2bf(sj.x), f2bf(sj.y), f2bf(sj.z), f2bf(sj.w)};
        *(ushort4*)&NISb[(size_t)n * 512 + 256 + l*4] = o;
    }
}

// ---------------- kA2u: U rows -> UT4 components 0..2 (validated r4-r8) ----------------
__global__ __launch_bounds__(256) void kA2u(
    const unsigned short* __restrict__ VJKb, const unsigned short* __restrict__ w1bt,
    float* __restrict__ UT4, int M)
{
    const int t  = threadIdx.x;
    const int l  = t & 63;
    const int w  = t >> 6;
    const int lm = l & 15, lq = l >> 4;

    bf16x8 bfr[4][8];
    #pragma unroll
    for (int ct = 0; ct < 4; ct++)
        #pragma unroll
        for (int kb = 0; kb < 8; kb++)
            bfr[ct][kb] = *(const bf16x8*)(w1bt + (size_t)(w*64 + ct*16 + lm) * 256 + kb*32 + lq*8);

    const int r00 = blockIdx.x * 128;
    #pragma unroll 1
    for (int mt = 0; mt < 8; mt++){
        const int r0 = r00 + mt * 16;
        bf16x8 af[8];
        #pragma unroll
        for (int kb = 0; kb < 8; kb++)
            af[kb] = *(const bf16x8*)(VJKb + (size_t)(r0 + lm) * 256 + kb*32 + lq*8);
        f32x4v acc[4];
        #pragma unroll
        for (int ct = 0; ct < 4; ct++) acc[ct] = (f32x4v){0.f,0.f,0.f,0.f};
        #pragma unroll
        for (int kb = 0; kb < 8; kb++)
            #pragma unroll
            for (int ct = 0; ct < 4; ct++)
                acc[ct] = __builtin_amdgcn_mfma_f32_16x16x32_bf16(af[kb], bfr[ct][kb], acc[ct], 0, 0, 0);
        #pragma unroll
        for (int ct = 0; ct < 4; ct++){
            const int col = w*64 + ct*16 + lm;
            #pragma unroll
            for (int r = 0; r < 4; r++){
                const int row = r0 + lq*4 + r;
                const int n = row / 3, c = row - n*3;
                UT4[(((size_t)n << 8) + col) * 4 + c] = acc[ct][r];
            }
        }
    }
}

// ---------------- kA2t: T -> UT4 component 3 (validated r4-r8) ----------------
__global__ __launch_bounds__(256) void kA2t(
    const unsigned short* __restrict__ NISb, const unsigned short* __restrict__ w1cdt,
    const float* __restrict__ msg_b1,
    float* __restrict__ UT4, int M)
{
    const int t  = threadIdx.x;
    const int l  = t & 63;
    const int w  = t >> 6;
    const int lm = l & 15, lq = l >> 4;

    const int ch = blockIdx.x & 1;
    const int bm = blockIdx.x >> 1;

    bf16x8 bfr[2][16];
    #pragma unroll
    for (int ct = 0; ct < 2; ct++)
        #pragma unroll
        for (int kb = 0; kb < 16; kb++)
            bfr[ct][kb] = *(const bf16x8*)(w1cdt + (size_t)(ch*128 + w*32 + ct*16 + lm) * 512 + kb*32 + lq*8);

    const int r00 = bm * 128;
    #pragma unroll 1
    for (int mt = 0; mt < 8; mt++){
        const int r0 = r00 + mt * 16;
        bf16x8 af[16];
        #pragma unroll
        for (int kb = 0; kb < 16; kb++)
            af[kb] = *(const bf16x8*)(NISb + (size_t)(r0 + lm) * 512 + kb*32 + lq*8);
        f32x4v acc[2];
        #pragma unroll
        for (int ct = 0; ct < 2; ct++) acc[ct] = (f32x4v){0.f,0.f,0.f,0.f};
        #pragma unroll
        for (int kb = 0; kb < 16; kb++)
            #pragma unroll
            for (int ct = 0; ct < 2; ct++)
                acc[ct] = __builtin_amdgcn_mfma_f32_16x16x32_bf16(af[kb], bfr[ct][kb], acc[ct], 0, 0, 0);
        #pragma unroll
        for (int ct = 0; ct < 2; ct++){
            const int col = ch*128 + w*32 + ct*16 + lm;
            const float bias = msg_b1[col];
            #pragma unroll
            for (int r = 0; r < 4; r++){
                const int n = r0 + lq*4 + r;
                UT4[(((size_t)n << 8) + col) * 4 + 3] = acc[ct][r] + bias;
            }
        }
    }
}

// ---------------- CSR binning ----------------
__global__ __launch_bounds__(256) void kHist(const int* __restrict__ pe, int* __restrict__ cnt, int E){
    int e = blockIdx.x * 256 + threadIdx.x;
    if (e < E) atomicAdd(&cnt[pe[(size_t)e*2]], 1);
}

__global__ __launch_bounds__(1024) void kScan(const int* __restrict__ cnt, int* __restrict__ off, int N){
    __shared__ int sums[1024];
    const int t = threadIdx.x;
    const int base = t * 8;
    int c[8]; int s = 0;
    #pragma unroll
    for (int j = 0; j < 8; j++){
        int v = (base + j < N) ? cnt[base + j] : 0;
        c[j] = s; s += v;
    }
    sums[t] = s;
    __syncthreads();
    for (int d = 1; d < 1024; d <<= 1){
        int v = (t >= d) ? sums[t - d] : 0;
        __syncthreads();
        sums[t] += v;
        __syncthreads();
    }
    int excl = (t == 0) ? 0 : sums[t - 1];
    #pragma unroll
    for (int j = 0; j < 8; j++)
        if (base + j < N) off[base + j] = excl + c[j];
    if (t == 1023) off[N] = sums[1023];
}

__global__ __launch_bounds__(256) void kScatter(const int* __restrict__ pe,
    const int* __restrict__ off, int* __restrict__ pos, int* __restrict__ perm, int E){
    int e = blockIdx.x * 256 + threadIdx.x;
    if (e < E){
        int i = pe[(size_t)e*2];
        int slot = atomicAdd(&pos[i], 1);
        perm[off[i] + slot] = e;
    }
}

// ---------------- kB1: fused geometry + edge MLP + scatter ----------------
// r9: 64-edge super-batches (2/block), 3 barriers each, double-buffered
// epi/meta, next batch geometry prefetched into registers.
__global__ __launch_bounds__(256) void kB1(
    const int* __restrict__ pe, const float* __restrict__ disp,
    const float* __restrict__ cell,
    const float* __restrict__ atom_xyz, const float* __restrict__ probe_xyz,
    const float* __restrict__ UT4,
    const float* __restrict__ msg_w1,
    const unsigned short* __restrict__ w2t, const float* __restrict__ msg_b2,
    const float* __restrict__ msg_w3, const float* __restrict__ msg_b3,
    const int* __restrict__ perm,
    float* __restrict__ rho, int E)
{
    __shared__ unsigned short x_lds[64 * 256];      // 32 KB, XOR-swizzled
    __shared__ unsigned short epi_b[2][64 * 40];    // 10 KB
    __shared__ int   ai_l[2][64];
    __shared__ int   pp_l[2][64];
    __shared__ float4 rc4_l[2][64];
    __shared__ float part[4][64];

    char* xbase = (char*)x_lds;

    const int t  = threadIdx.x;
    const int l  = t & 63;
    const int w  = t >> 6;
    const int lq = l >> 4;
    const int lm = l & 15;
    const int slot = t >> 2, q = t & 3;

    const float c0 = cell[0], c1 = cell[1], c2 = cell[2];
    const float c3 = cell[3], c4 = cell[4], c5 = cell[5];
    const float c6 = cell[6], c7 = cell[7], c8 = cell[8];

    bf16x8 w1afr[4];
    #pragma unroll
    for (int nt = 0; nt < 4; nt++){
        const int col = w*64 + nt*16 + lm;
        bf16x8 v;
        #pragma unroll
        for (int j = 0; j < 8; j++)
            v[j] = (short)f2bf(msg_w1[(size_t)(lq*8 + j) * F_DIM + col]);
        w1afr[nt] = v;
    }

    bf16x8 bfr[2][8];
    #pragma unroll
    for (int nt2 = 0; nt2 < 2; nt2++){
        const int h = w*32 + nt2*16 + lm;
        #pragma unroll
        for (int kb = 0; kb < 8; kb++)
            bfr[nt2][kb] = *(const bf16x8*)(w2t + (size_t)h * F_DIM + kb*32 + lq*8);
    }
    const float b2v0 = msg_b2[w*32 + lm];
    const float b2v1 = msg_b2[w*32 + 16 + lm];
    const float w3v0 = msg_w3[w*32 + lm];
    const float w3v1 = msg_w3[w*32 + 16 + lm];
    const float b3   = msg_b3[0];

    const int e0 = blockIdx.x * 128;

    // geometry registers for both batches (set bb loaded during bb-1 compute)
    int ee_r[2], ia_r[2], ip_r[2];
    float gd[2][3], gp[2][3], ga[2][3];

    {   // prologue: batch 0 geometry chain
        int s = min(e0 + slot, E - 1);
        ee_r[0] = perm[s];
        ia_r[0] = pe[(size_t)ee_r[0]*2];
        ip_r[0] = pe[(size_t)ee_r[0]*2 + 1];
        gd[0][0] = disp[(size_t)ee_r[0]*3];   gd[0][1] = disp[(size_t)ee_r[0]*3+1]; gd[0][2] = disp[(size_t)ee_r[0]*3+2];
        gp[0][0] = probe_xyz[(size_t)ip_r[0]*3]; gp[0][1] = probe_xyz[(size_t)ip_r[0]*3+1]; gp[0][2] = probe_xyz[(size_t)ip_r[0]*3+2];
        ga[0][0] = atom_xyz[(size_t)ia_r[0]*3];  ga[0][1] = atom_xyz[(size_t)ia_r[0]*3+1];  ga[0][2] = atom_xyz[(size_t)ia_r[0]*3+2];
    }

    #pragma unroll
    for (int bb = 0; bb < 2; bb++){
        const int e0b = e0 + bb * 64;

        // ---- stage: geometry + 8 RBF sins per thread (4 threads/edge) ----
        {
            const float sx = gd[bb][0]*c0 + gd[bb][1]*c3 + gd[bb][2]*c6;
            const float sy = gd[bb][0]*c1 + gd[bb][1]*c4 + gd[bb][2]*c7;
            const float sz = gd[bb][0]*c2 + gd[bb][1]*c5 + gd[bb][2]*c8;
            const float dx = gp[bb][0] - (ga[bb][0] + sx);
            const float dy = gp[bb][1] - (ga[bb][1] + sy);
            const float dz = gp[bb][2] - (ga[bb][2] + sz);
            const float dist = sqrtf(dx*dx + dy*dy + dz*dz);
            const float inv  = 1.f / (dist + 1e-8f);
            const float base = dist * (PI_F / CUTOFF_F);
            ushort4 ea, eb;
            ea.x = f2bf(__sinf(base * (float)(q*8 + 1)) * inv);
            ea.y = f2bf(__sinf(base * (float)(q*8 + 2)) * inv);
            ea.z = f2bf(__sinf(base * (float)(q*8 + 3)) * inv);
            ea.w = f2bf(__sinf(base * (float)(q*8 + 4)) * inv);
            eb.x = f2bf(__sinf(base * (float)(q*8 + 5)) * inv);
            eb.y = f2bf(__sinf(base * (float)(q*8 + 6)) * inv);
            eb.z = f2bf(__sinf(base * (float)(q*8 + 7)) * inv);
            eb.w = f2bf(__sinf(base * (float)(q*8 + 8)) * inv);
            *(ushort4*)&epi_b[bb][slot*40 + q*8]     = ea;
            *(ushort4*)&epi_b[bb][slot*40 + q*8 + 4] = eb;
            if (q == 0){
                ai_l[bb][slot] = ia_r[bb];
                pp_l[bb][slot] = ip_r[bb];
                float cw = (dist < CUTOFF_F) ? 0.5f * (__cosf(base) + 1.f) : 0.f;
                rc4_l[bb][slot] = (float4){dx*inv, dy*inv, dz*inv, cw};
            }
        }

        // issue next batch's geometry chain (overlaps with compute below)
        if (bb == 0){
            int s = min(e0 + 64 + slot, E - 1);
            ee_r[1] = perm[s];
            ia_r[1] = pe[(size_t)ee_r[1]*2];
            ip_r[1] = pe[(size_t)ee_r[1]*2 + 1];
            gd[1][0] = disp[(size_t)ee_r[1]*3];   gd[1][1] = disp[(size_t)ee_r[1]*3+1]; gd[1][2] = disp[(size_t)ee_r[1]*3+2];
            gp[1][0] = probe_xyz[(size_t)ip_r[1]*3]; gp[1][1] = probe_xyz[(size_t)ip_r[1]*3+1]; gp[1][2] = probe_xyz[(size_t)ip_r[1]*3+2];
            ga[1][0] = atom_xyz[(size_t)ia_r[1]*3];  ga[1][1] = atom_xyz[(size_t)ia_r[1]*3+1];  ga[1][2] = atom_xyz[(size_t)ia_r[1]*3+2];
        }
        __syncthreads();   // stage visible

        // ---- MFMA1 + epilogue, two halves of 32 edges ----
        #pragma unroll
        for (int hh = 0; hh < 2; hh++){
            f32x4v pacc[2][4];
            #pragma unroll
            for (int mt = 0; mt < 2; mt++)
                #pragma unroll
                for (int nt = 0; nt < 4; nt++) pacc[mt][nt] = (f32x4v){0.f,0.f,0.f,0.f};
            #pragma unroll
            for (int mt = 0; mt < 2; mt++){
                const bf16x8 af = *(const bf16x8*)&epi_b[bb][(hh*32 + mt*16 + lm)*40 + lq*8];
                #pragma unroll
                for (int nt = 0; nt < 4; nt++)
                    pacc[mt][nt] = __builtin_amdgcn_mfma_f32_16x16x32_bf16(af, w1afr[nt], pacc[mt][nt], 0, 0, 0);
            }
            #pragma unroll
            for (int mt = 0; mt < 2; mt++){
                #pragma unroll
                for (int r = 0; r < 4; r++){
                    const int e = hh*32 + mt*16 + lq*4 + r;
                    const int i = ai_l[bb][e];
                    const float4 rc = rc4_l[bb][e];
                    const float* up = UT4 + ((size_t)i << 10);
                    #pragma unroll
                    for (int nt = 0; nt < 4; nt++){
                        const int col = w*64 + nt*16 + lm;
                        const float4 ut = *(const float4*)(up + (size_t)col * 4);
                        float z = pacc[mt][nt][r] + ut.w;
                        z = fmaf(rc.x, ut.x, fmaf(rc.y, ut.y, fmaf(rc.z, ut.z, z)));
                        const int wofs = e*512 + ((col*2) ^ ((e & 7) << 4));
                        *(unsigned short*)(xbase + wofs) = f2bf(silu_f(z));
                    }
                }
            }
        }
        __syncthreads();   // x_lds ready

        // ---- MFMA2: 64 edges x 128 h ----
        f32x4v acc[4][2];
        #pragma unroll
        for (int m = 0; m < 4; m++){
            acc[m][0] = (f32x4v){0.f,0.f,0.f,0.f};
            acc[m][1] = (f32x4v){0.f,0.f,0.f,0.f};
        }
        #pragma unroll
        for (int kb = 0; kb < 8; kb++){
            const int ko = kb*64 + lq*16;
            #pragma unroll
            for (int m = 0; m < 4; m++){
                const int eA = m*16 + lm;
                bf16x8 af = *(const bf16x8*)(xbase + eA*512 + (ko ^ ((eA & 7) << 4)));
                acc[m][0] = __builtin_amdgcn_mfma_f32_16x16x32_bf16(af, bfr[0][kb], acc[m][0], 0, 0, 0);
                acc[m][1] = __builtin_amdgcn_mfma_f32_16x16x32_bf16(af, bfr[1][kb], acc[m][1], 0, 0, 0);
            }
        }

        // ---- layer 3: silu, *w3, reduce over h ----
        #pragma unroll
        for (int m = 0; m < 4; m++){
            float pr[4];
            #pragma unroll
            for (int r = 0; r < 4; r++)
                pr[r] = silu_f(acc[m][0][r] + b2v0) * w3v0 + silu_f(acc[m][1][r] + b2v1) * w3v1;
            #pragma unroll
            for (int r = 0; r < 4; r++){
                #pragma unroll
                for (int mm = 8; mm >= 1; mm >>= 1)
                    pr[r] += __shfl_xor(pr[r], mm, 64);
            }
            if (lm == 0){
                #pragma unroll
                for (int r = 0; r < 4; r++)
                    part[w][m*16 + lq*4 + r] = pr[r];
            }
        }
        __syncthreads();   // part ready (also fences x_lds reuse)

        if (t < 64 && (e0b + t) < E){
            float tot = part[0][t] + part[1][t] + part[2][t] + part[3][t] + b3;
            atomicAdd(&rho[pp_l[bb][t]], tot * rc4_l[bb][t].w);
        }
        // no trailing barrier: next stage writes epi/meta[bb^1]; part reuse is
        // fenced by next iteration's two barriers before its part write.
    }
}

extern "C" void kernel_launch(void* const* d_in, const int* in_sizes, int n_in,
                              void* d_out, int out_size, void* d_ws, size_t ws_size,
                              hipStream_t stream)
{
    const float* s_stack   = (const float*)d_in[0];
    const float* v_stack   = (const float*)d_in[1];
    const float* atom_xyz  = (const float*)d_in[2];
    const float* probe_xyz = (const float*)d_in[3];
    const float* cell      = (const float*)d_in[4];
    const float* disp      = (const float*)d_in[5];
    const float* attn_w1   = (const float*)d_in[6];
    const float* attn_b1   = (const float*)d_in[7];
    const float* attn_w2   = (const float*)d_in[8];
    const float* msg_w1    = (const float*)d_in[10];
    const float* msg_b1    = (const float*)d_in[11];
    const float* msg_w2    = (const float*)d_in[12];
    const float* msg_b2    = (const float*)d_in[13];
    const float* msg_w3    = (const float*)d_in[14];
    const float* msg_b3    = (const float*)d_in[15];
    const int*   pe        = (const int*)d_in[16];

    const int N = in_sizes[0] / (L_DIM * F_DIM);
    const int E = in_sizes[16] / 2;
    const int P = out_size;
    const size_t NF = (size_t)N * F_DIM;

    float* ws = (float*)d_ws;
    unsigned short* VJKb = (unsigned short*)ws;            // 3N x 256 bf16 (1.5 NF fl)
    unsigned short* NISb = VJKb + 3*NF;                    // N x 512 bf16  (1.0 NF fl)
    float* UT4 = ws + (5*NF)/2;                            // N x 256 x 4 f32 (4 NF fl)
    unsigned short* w1bt  = (unsigned short*)(ws + (13*NF)/2);  // 256x256 bf16
    unsigned short* w1cdt = w1bt + 65536;                  // 256x512 bf16
    unsigned short* w2t   = w1cdt + 131072;                // 128x256 bf16
    unsigned short* wA1t  = w2t + 32768;                   // 128x256 bf16
    int* cnt  = (int*)(wA1t + 32768);
    int* pos  = cnt + N;
    int* offs = pos + N;
    int* perm = offs + N + 1;

    hipMemsetAsync(d_out, 0, (size_t)P * sizeof(float), stream);
    hipMemsetAsync(cnt, 0, 2 * (size_t)N * sizeof(int), stream);

    kPrep<<<1024, 256, 0, stream>>>(msg_w1, msg_w2, attn_w1, w1bt, w1cdt, w2t, wA1t);

    kAW<<<(N + 15) / 16, 256, 0, stream>>>(s_stack, v_stack, wA1t, attn_b1, attn_w2,
                                           VJKb, NISb, N);

    kA2u<<<(3 * N) / 128, 256, 0, stream>>>(VJKb, w1bt, UT4, 3 * N);
    kA2t<<<(N / 128) * 2, 256, 0, stream>>>(NISb, w1cdt, msg_b1, UT4, N);

    const int gE = (E + 255) / 256;
    kHist<<<gE, 256, 0, stream>>>(pe, cnt, E);
    kScan<<<1, 1024, 0, stream>>>(cnt, offs, N);
    kScatter<<<gE, 256, 0, stream>>>(pe, offs, pos, perm, E);

    kB1<<<(E + 127) / 128, 256, 0, stream>>>(pe, disp, cell, atom_xyz, probe_xyz,
                                             UT4, msg_w1,
                                             w2t, msg_b2, msg_w3, msg_b3,
                                             perm, (float*)d_out, E);
}

// Round 10
// 190.402 us; speedup vs baseline: 1.2788x; 1.0739x over previous
//
#include <hip/hip_runtime.h>
#include <math.h>
#include <stdint.h>

// PaiNN QM encoder, round 10.
//   U = V_JK @ W1b  (N,3,256)   T = b1 + n_i@W1c + S_JK@W1d  (N,256)
//   per edge: x = silu(T[i] + e_pi@W1a + r_hat.U[i]); m = (silu(x@W2+b2))@w3+b3
// r10: kB1 reverted to the r8 version (measured 84us; r9's 64-edge superbatch
// regressed to 124us via LDS-driven occupancy loss). kAW kept (validated r9).
// kA2u+kA2t merged into one dispatch; memsets folded into kPrep's grid tail.

#define L_DIM 6
#define F_DIM 256
#define FH_DIM 128
#define DRBF 32
#define CUTOFF_F 4.0f
#define PI_F 3.14159265358979323846f

using bf16x8 = __attribute__((ext_vector_type(8))) short;
using f32x4v = __attribute__((ext_vector_type(4))) float;

__device__ __forceinline__ float silu_f(float x){ return x / (1.f + __expf(-x)); }

__device__ __forceinline__ unsigned short f2bf(float f){
    uint32_t u = __float_as_uint(f);
    uint32_t r = (u + 0x7fffu + ((u >> 16) & 1u)) >> 16;   // RNE
    return (unsigned short)r;
}

// ---------------- kPrep: weight transpose/convert + output/CSR zeroing ----------------
__global__ __launch_bounds__(256) void kPrep(
    const float* __restrict__ msg_w1, const float* __restrict__ msg_w2,
    const float* __restrict__ attn_w1,
    unsigned short* __restrict__ w1bt, unsigned short* __restrict__ w1cdt,
    unsigned short* __restrict__ w2t, unsigned short* __restrict__ wA1t,
    float* __restrict__ rho, int P, int* __restrict__ cntpos, int CN)
{
    int idx = blockIdx.x * 256 + threadIdx.x;
    if (idx < 65536){
        int k = idx >> 8, j = idx & 255;
        w1bt[(size_t)j * 256 + k] = f2bf(msg_w1[(size_t)(DRBF + k) * F_DIM + j]);
    } else if (idx < 196608){
        int i2 = idx - 65536;
        int k = i2 >> 8, j = i2 & 255;
        w1cdt[(size_t)j * 512 + k] = f2bf(msg_w1[(size_t)(DRBF + 256 + k) * F_DIM + j]);
    } else if (idx < 229376){
        int i3 = idx - 196608;
        int k = i3 >> 7, h = i3 & 127;
        w2t[(size_t)h * 256 + k] = f2bf(msg_w2[(size_t)k * FH_DIM + h]);
    } else if (idx < 262144){
        int i4 = idx - 229376;
        int j = i4 >> 8, k = i4 & 255;
        wA1t[(size_t)j * 256 + k] = f2bf(attn_w1[(size_t)k * FH_DIM + j]);
    } else if (idx < 262144 + 32768){
        int i5 = idx - 262144;
        if (i5 < P) rho[i5] = 0.f;
    } else {
        int i6 = idx - 262144 - 32768;
        if (i6 < CN) cntpos[i6] = 0;
    }
}

// ---------------- kAW: fused attention (MFMA logits + softmax + v-stream, validated r9) ----------------
__global__ __launch_bounds__(256) void kAW(
    const float* __restrict__ s_stack, const float* __restrict__ v_stack,
    const unsigned short* __restrict__ wA1t,
    const float* __restrict__ attn_b1, const float* __restrict__ attn_w2,
    unsigned short* __restrict__ VJKb, unsigned short* __restrict__ NISb, int N)
{
    __shared__ float part[4][96];
    __shared__ float aw_l[16][8];

    const int t  = threadIdx.x;
    const int l  = t & 63;
    const int w  = t >> 6;
    const int lm = l & 15, lq = l >> 4;

    bf16x8 bfr[2][8];
    #pragma unroll
    for (int nt2 = 0; nt2 < 2; nt2++){
        const int col = w*32 + nt2*16 + lm;
        #pragma unroll
        for (int kb = 0; kb < 8; kb++)
            bfr[nt2][kb] = *(const bf16x8*)(wA1t + (size_t)col * 256 + kb*32 + lq*8);
    }
    const float b1a = attn_b1[w*32 + lm];
    const float b1b = attn_b1[w*32 + 16 + lm];
    const float w2a = attn_w2[w*32 + lm];
    const float w2b = attn_w2[w*32 + 16 + lm];

    const int n0 = blockIdx.x * 16;
    const size_t rbase = (size_t)n0 * L_DIM;
    const size_t rmax  = (size_t)N * L_DIM - 1;

    // ---- phase 1: logits ----
    #pragma unroll
    for (int mt = 0; mt < 6; mt++){
        const size_t r0 = rbase + mt * 16;
        bf16x8 af[8];
        #pragma unroll
        for (int kb = 0; kb < 8; kb++){
            size_t row = r0 + lm; if (row > rmax) row = rmax;
            const float* ap = s_stack + row * 256 + kb*32 + lq*8;
            float4 fa = *(const float4*)ap;
            float4 fb = *(const float4*)(ap + 4);
            bf16x8 v;
            v[0] = (short)f2bf(fa.x); v[1] = (short)f2bf(fa.y);
            v[2] = (short)f2bf(fa.z); v[3] = (short)f2bf(fa.w);
            v[4] = (short)f2bf(fb.x); v[5] = (short)f2bf(fb.y);
            v[6] = (short)f2bf(fb.z); v[7] = (short)f2bf(fb.w);
            af[kb] = v;
        }
        f32x4v a0 = {0.f,0.f,0.f,0.f}, a1 = {0.f,0.f,0.f,0.f};
        #pragma unroll
        for (int kb = 0; kb < 8; kb++){
            a0 = __builtin_amdgcn_mfma_f32_16x16x32_bf16(af[kb], bfr[0][kb], a0, 0, 0, 0);
            a1 = __builtin_amdgcn_mfma_f32_16x16x32_bf16(af[kb], bfr[1][kb], a1, 0, 0, 0);
        }
        #pragma unroll
        for (int r = 0; r < 4; r++){
            float p = silu_f(a0[r] + b1a) * w2a + silu_f(a1[r] + b1b) * w2b;
            #pragma unroll
            for (int m = 8; m >= 1; m >>= 1) p += __shfl_xor(p, m, 64);
            if (lm == 0) part[w][mt*16 + lq*4 + r] = p;
        }
    }
    __syncthreads();
    if (t < 96) part[0][t] = part[0][t] + part[1][t] + part[2][t] + part[3][t];
    __syncthreads();
    if (t < 16){
        float e[L_DIM]; float mx = -1e30f;
        #pragma unroll
        for (int l6 = 0; l6 < L_DIM; l6++) mx = fmaxf(mx, part[0][t*L_DIM + l6]);
        float s = 0.f;
        #pragma unroll
        for (int l6 = 0; l6 < L_DIM; l6++){ e[l6] = __expf(part[0][t*L_DIM + l6] - mx); s += e[l6]; }
        float inv = 1.f / s;
        #pragma unroll
        for (int l6 = 0; l6 < L_DIM; l6++) aw_l[t][l6] = e[l6] * inv;
    }
    __syncthreads();

    // ---- phase 2: weighted sums (wave handles 4 atoms) ----
    #pragma unroll 1
    for (int aa = 0; aa < 4; aa++){
        const int n = min(n0 + w*4 + aa, N - 1);
        float aw[L_DIM];
        #pragma unroll
        for (int l6 = 0; l6 < L_DIM; l6++) aw[l6] = aw_l[w*4 + aa][l6];

        const float* sp = s_stack + (size_t)n * (L_DIM * F_DIM) + l * 4;
        const float* vp = v_stack + (size_t)n * (L_DIM * 3 * F_DIM) + l * 4;
        float4 v0 = {0.f,0.f,0.f,0.f}, v1 = {0.f,0.f,0.f,0.f}, v2 = {0.f,0.f,0.f,0.f};
        float4 sj = {0.f,0.f,0.f,0.f};
        #pragma unroll
        for (int l6 = 0; l6 < L_DIM; l6++){
            const float a = aw[l6];
            float4 ss = *(const float4*)(sp + (size_t)l6 * F_DIM);
            float4 x0 = *(const float4*)(vp + (size_t)(l6*3+0) * F_DIM);
            float4 x1 = *(const float4*)(vp + (size_t)(l6*3+1) * F_DIM);
            float4 x2 = *(const float4*)(vp + (size_t)(l6*3+2) * F_DIM);
            v0.x = fmaf(a, x0.x, v0.x); v0.y = fmaf(a, x0.y, v0.y);
            v0.z = fmaf(a, x0.z, v0.z); v0.w = fmaf(a, x0.w, v0.w);
            v1.x = fmaf(a, x1.x, v1.x); v1.y = fmaf(a, x1.y, v1.y);
            v1.z = fmaf(a, x1.z, v1.z); v1.w = fmaf(a, x1.w, v1.w);
            v2.x = fmaf(a, x2.x, v2.x); v2.y = fmaf(a, x2.y, v2.y);
            v2.z = fmaf(a, x2.z, v2.z); v2.w = fmaf(a, x2.w, v2.w);
            sj.x = fmaf(a, ss.x, sj.x); sj.y = fmaf(a, ss.y, sj.y);
            sj.z = fmaf(a, ss.z, sj.z); sj.w = fmaf(a, ss.w, sj.w);
        }
        float4 ni;
        ni.x = sqrtf(v0.x*v0.x + v1.x*v1.x + v2.x*v2.x);
        ni.y = sqrtf(v0.y*v0.y + v1.y*v1.y + v2.y*v2.y);
        ni.z = sqrtf(v0.z*v0.z + v1.z*v1.z + v2.z*v2.z);
        ni.w = sqrtf(v0.w*v0.w + v1.w*v1.w + v2.w*v2.w);

        ushort4 o;
        o = (ushort4){f2bf(v0.x), f2bf(v0.y), f2bf(v0.z), f2bf(v0.w)};
        *(ushort4*)&VJKb[((size_t)n*3 + 0) * F_DIM + l*4] = o;
        o = (ushort4){f2bf(v1.x), f2bf(v1.y), f2bf(v1.z), f2bf(v1.w)};
        *(ushort4*)&VJKb[((size_t)n*3 + 1) * F_DIM + l*4] = o;
        o = (ushort4){f2bf(v2.x), f2bf(v2.y), f2bf(v2.z), f2bf(v2.w)};
        *(ushort4*)&VJKb[((size_t)n*3 + 2) * F_DIM + l*4] = o;
        o = (ushort4){f2bf(ni.x), f2bf(ni.y), f2bf(ni.z), f2bf(ni.w)};
        *(ushort4*)&NISb[(size_t)n * 512 + l*4] = o;
        o = (ushort4){f2bf(sj.x), f2bf(sj.y), f2bf(sj.z), f2bf(sj.w)};
        *(ushort4*)&NISb[(size_t)n * 512 + 256 + l*4] = o;
    }
}

// ---------------- kA2: merged U (blocks < gU) and T (blocks >= gU) -> UT4 ----------------
__global__ __launch_bounds__(256) void kA2(
    const unsigned short* __restrict__ VJKb, const unsigned short* __restrict__ w1bt,
    const unsigned short* __restrict__ NISb, const unsigned short* __restrict__ w1cdt,
    const float* __restrict__ msg_b1,
    float* __restrict__ UT4, int gU)
{
    const int t  = threadIdx.x;
    const int l  = t & 63;
    const int w  = t >> 6;
    const int lm = l & 15, lq = l >> 4;

    if ((int)blockIdx.x < gU){
        // ---- U = VJKb @ W1b (validated r4-r9), rows of (3N,256) ----
        bf16x8 bfr[4][8];
        #pragma unroll
        for (int ct = 0; ct < 4; ct++)
            #pragma unroll
            for (int kb = 0; kb < 8; kb++)
                bfr[ct][kb] = *(const bf16x8*)(w1bt + (size_t)(w*64 + ct*16 + lm) * 256 + kb*32 + lq*8);

        const int r00 = blockIdx.x * 128;
        #pragma unroll 1
        for (int mt = 0; mt < 8; mt++){
            const int r0 = r00 + mt * 16;
            bf16x8 af[8];
            #pragma unroll
            for (int kb = 0; kb < 8; kb++)
                af[kb] = *(const bf16x8*)(VJKb + (size_t)(r0 + lm) * 256 + kb*32 + lq*8);
            f32x4v acc[4];
            #pragma unroll
            for (int ct = 0; ct < 4; ct++) acc[ct] = (f32x4v){0.f,0.f,0.f,0.f};
            #pragma unroll
            for (int kb = 0; kb < 8; kb++)
                #pragma unroll
                for (int ct = 0; ct < 4; ct++)
                    acc[ct] = __builtin_amdgcn_mfma_f32_16x16x32_bf16(af[kb], bfr[ct][kb], acc[ct], 0, 0, 0);
            #pragma unroll
            for (int ct = 0; ct < 4; ct++){
                const int col = w*64 + ct*16 + lm;
                #pragma unroll
                for (int r = 0; r < 4; r++){
                    const int row = r0 + lq*4 + r;
                    const int n = row / 3, c = row - n*3;
                    UT4[(((size_t)n << 8) + col) * 4 + c] = acc[ct][r];
                }
            }
        }
    } else {
        // ---- T = b1 + NISb @ W1cd (K=512, validated r4-r9) ----
        const int bid = blockIdx.x - gU;
        const int ch = bid & 1;
        const int bm = bid >> 1;

        bf16x8 bfr[2][16];
        #pragma unroll
        for (int ct = 0; ct < 2; ct++)
            #pragma unroll
            for (int kb = 0; kb < 16; kb++)
                bfr[ct][kb] = *(const bf16x8*)(w1cdt + (size_t)(ch*128 + w*32 + ct*16 + lm) * 512 + kb*32 + lq*8);

        const int r00 = bm * 128;
        #pragma unroll 1
        for (int mt = 0; mt < 8; mt++){
            const int r0 = r00 + mt * 16;
            bf16x8 af[16];
            #pragma unroll
            for (int kb = 0; kb < 16; kb++)
                af[kb] = *(const bf16x8*)(NISb + (size_t)(r0 + lm) * 512 + kb*32 + lq*8);
            f32x4v acc[2];
            #pragma unroll
            for (int ct = 0; ct < 2; ct++) acc[ct] = (f32x4v){0.f,0.f,0.f,0.f};
            #pragma unroll
            for (int kb = 0; kb < 16; kb++)
                #pragma unroll
                for (int ct = 0; ct < 2; ct++)
                    acc[ct] = __builtin_amdgcn_mfma_f32_16x16x32_bf16(af[kb], bfr[ct][kb], acc[ct], 0, 0, 0);
            #pragma unroll
            for (int ct = 0; ct < 2; ct++){
                const int col = ch*128 + w*32 + ct*16 + lm;
                const float bias = msg_b1[col];
                #pragma unroll
                for (int r = 0; r < 4; r++){
                    const int n = r0 + lq*4 + r;
                    UT4[(((size_t)n << 8) + col) * 4 + 3] = acc[ct][r] + bias;
                }
            }
        }
    }
}

// ---------------- CSR binning ----------------
__global__ __launch_bounds__(256) void kHist(const int* __restrict__ pe, int* __restrict__ cnt, int E){
    int e = blockIdx.x * 256 + threadIdx.x;
    if (e < E) atomicAdd(&cnt[pe[(size_t)e*2]], 1);
}

__global__ __launch_bounds__(1024) void kScan(const int* __restrict__ cnt, int* __restrict__ off, int N){
    __shared__ int sums[1024];
    const int t = threadIdx.x;
    const int base = t * 8;
    int c[8]; int s = 0;
    #pragma unroll
    for (int j = 0; j < 8; j++){
        int v = (base + j < N) ? cnt[base + j] : 0;
        c[j] = s; s += v;
    }
    sums[t] = s;
    __syncthreads();
    for (int d = 1; d < 1024; d <<= 1){
        int v = (t >= d) ? sums[t - d] : 0;
        __syncthreads();
        sums[t] += v;
        __syncthreads();
    }
    int excl = (t == 0) ? 0 : sums[t - 1];
    #pragma unroll
    for (int j = 0; j < 8; j++)
        if (base + j < N) off[base + j] = excl + c[j];
    if (t == 1023) off[N] = sums[1023];
}

__global__ __launch_bounds__(256) void kScatter(const int* __restrict__ pe,
    const int* __restrict__ off, int* __restrict__ pos, int* __restrict__ perm, int E){
    int e = blockIdx.x * 256 + threadIdx.x;
    if (e < E){
        int i = pe[(size_t)e*2];
        int slot = atomicAdd(&pos[i], 1);
        perm[off[i] + slot] = e;
    }
}

// ---------------- kB1: fused geometry + edge MLP + scatter (r8 version, measured 84us) ----------------
__global__ __launch_bounds__(256) void kB1(
    const int* __restrict__ pe, const float* __restrict__ disp,
    const float* __restrict__ cell,
    const float* __restrict__ atom_xyz, const float* __restrict__ probe_xyz,
    const float* __restrict__ UT4,
    const float* __restrict__ msg_w1,
    const unsigned short* __restrict__ w2t, const float* __restrict__ msg_b2,
    const float* __restrict__ msg_w3, const float* __restrict__ msg_b3,
    const int* __restrict__ perm,
    float* __restrict__ rho, int E)
{
    __shared__ unsigned short x_lds[32 * 256];   // 16 KB, XOR-swizzled
    __shared__ unsigned short epi_b[32 * 40];    // 2.5 KB, bf16 A-tile (pad 40)
    __shared__ int   ai_l[32];
    __shared__ int   pp_l[32];
    __shared__ float4 rc4_l[32];
    __shared__ float part[4][32];

    char* xbase = (char*)x_lds;

    const int t  = threadIdx.x;
    const int l  = t & 63;
    const int w  = t >> 6;
    const int lq = l >> 4;
    const int lm = l & 15;

    const float c0 = cell[0], c1 = cell[1], c2 = cell[2];
    const float c3 = cell[3], c4 = cell[4], c5 = cell[5];
    const float c6 = cell[6], c7 = cell[7], c8 = cell[8];

    bf16x8 w1afr[4];
    #pragma unroll
    for (int nt = 0; nt < 4; nt++){
        const int col = w*64 + nt*16 + lm;
        bf16x8 v;
        #pragma unroll
        for (int j = 0; j < 8; j++)
            v[j] = (short)f2bf(msg_w1[(size_t)(lq*8 + j) * F_DIM + col]);
        w1afr[nt] = v;
    }

    bf16x8 bfr[2][8];
    #pragma unroll
    for (int nt2 = 0; nt2 < 2; nt2++){
        const int h = w*32 + nt2*16 + lm;
        #pragma unroll
        for (int kb = 0; kb < 8; kb++)
            bfr[nt2][kb] = *(const bf16x8*)(w2t + (size_t)h * F_DIM + kb*32 + lq*8);
    }
    const float b2v0 = msg_b2[w*32 + lm];
    const float b2v1 = msg_b2[w*32 + 16 + lm];
    const float w3v0 = msg_w3[w*32 + lm];
    const float w3v1 = msg_w3[w*32 + 16 + lm];
    const float b3   = msg_b3[0];

    const int e0 = blockIdx.x * 128;

    // prefetch per-batch edge metadata (slot = t>>3 for each batch)
    int ee_r[4], ia_r[4], ip_r[4];
    #pragma unroll
    for (int bb = 0; bb < 4; bb++){
        int s = min(e0 + bb*32 + (t >> 3), E - 1);
        ee_r[bb] = perm[s];
    }
    #pragma unroll
    for (int bb = 0; bb < 4; bb++){
        ia_r[bb] = pe[(size_t)ee_r[bb]*2];
        ip_r[bb] = pe[(size_t)ee_r[bb]*2 + 1];
    }

    #pragma unroll 1
    for (int bb = 0; bb < 4; bb++){
        const int e0b = e0 + bb * 32;

        {
            const int slot = t >> 3, q = t & 7;
            const int ee = ee_r[bb];
            const int ia = ia_r[bb];
            const int ip = ip_r[bb];
            const float d0 = disp[(size_t)ee*3], d1 = disp[(size_t)ee*3+1], d2 = disp[(size_t)ee*3+2];
            const float sx = d0*c0 + d1*c3 + d2*c6;
            const float sy = d0*c1 + d1*c4 + d2*c7;
            const float sz = d0*c2 + d1*c5 + d2*c8;
            const float dx = probe_xyz[(size_t)ip*3+0] - (atom_xyz[(size_t)ia*3+0] + sx);
            const float dy = probe_xyz[(size_t)ip*3+1] - (atom_xyz[(size_t)ia*3+1] + sy);
            const float dz = probe_xyz[(size_t)ip*3+2] - (atom_xyz[(size_t)ia*3+2] + sz);
            const float dist = sqrtf(dx*dx + dy*dy + dz*dz);
            const float inv  = 1.f / (dist + 1e-8f);
            const float base = dist * (PI_F / CUTOFF_F);
            ushort4 eb;
            eb.x = f2bf(__sinf(base * (float)(q*4 + 1)) * inv);
            eb.y = f2bf(__sinf(base * (float)(q*4 + 2)) * inv);
            eb.z = f2bf(__sinf(base * (float)(q*4 + 3)) * inv);
            eb.w = f2bf(__sinf(base * (float)(q*4 + 4)) * inv);
            *(ushort4*)&epi_b[slot*40 + q*4] = eb;
            if (q == 0){
                ai_l[slot] = ia;
                pp_l[slot] = ip;
                float cw = (dist < CUTOFF_F) ? 0.5f * (__cosf(base) + 1.f) : 0.f;
                rc4_l[slot] = (float4){dx*inv, dy*inv, dz*inv, cw};
            }
        }
        __syncthreads();

        f32x4v pacc[2][4];
        #pragma unroll
        for (int mt = 0; mt < 2; mt++)
            #pragma unroll
            for (int nt = 0; nt < 4; nt++) pacc[mt][nt] = (f32x4v){0.f,0.f,0.f,0.f};
        #pragma unroll
        for (int mt = 0; mt < 2; mt++){
            const bf16x8 af = *(const bf16x8*)&epi_b[(mt*16 + lm)*40 + lq*8];
            #pragma unroll
            for (int nt = 0; nt < 4; nt++)
                pacc[mt][nt] = __builtin_amdgcn_mfma_f32_16x16x32_bf16(af, w1afr[nt], pacc[mt][nt], 0, 0, 0);
        }

        #pragma unroll
        for (int mt = 0; mt < 2; mt++){
            #pragma unroll
            for (int r = 0; r < 4; r++){
                const int e = mt*16 + lq*4 + r;
                const int i = ai_l[e];
                const float4 rc = rc4_l[e];
                const float* up = UT4 + ((size_t)i << 10);
                #pragma unroll
                for (int nt = 0; nt < 4; nt++){
                    const int col = w*64 + nt*16 + lm;
                    const float4 ut = *(const float4*)(up + (size_t)col * 4);
                    float z = pacc[mt][nt][r] + ut.w;
                    z = fmaf(rc.x, ut.x, fmaf(rc.y, ut.y, fmaf(rc.z, ut.z, z)));
                    const int wofs = e*512 + ((col*2) ^ ((e & 7) << 4));
                    *(unsigned short*)(xbase + wofs) = f2bf(silu_f(z));
                }
            }
        }
        __syncthreads();

        f32x4v acc00 = {0.f,0.f,0.f,0.f}, acc01 = {0.f,0.f,0.f,0.f};
        f32x4v acc10 = {0.f,0.f,0.f,0.f}, acc11 = {0.f,0.f,0.f,0.f};
        const int eA0 = lm;
        const int eA1 = 16 + lm;
        #pragma unroll
        for (int kb = 0; kb < 8; kb++){
            const int ko = kb*64 + lq*16;
            bf16x8 af0 = *(const bf16x8*)(xbase + eA0*512 + (ko ^ ((eA0 & 7) << 4)));
            bf16x8 af1 = *(const bf16x8*)(xbase + eA1*512 + (ko ^ ((eA1 & 7) << 4)));
            acc00 = __builtin_amdgcn_mfma_f32_16x16x32_bf16(af0, bfr[0][kb], acc00, 0, 0, 0);
            acc01 = __builtin_amdgcn_mfma_f32_16x16x32_bf16(af0, bfr[1][kb], acc01, 0, 0, 0);
            acc10 = __builtin_amdgcn_mfma_f32_16x16x32_bf16(af1, bfr[0][kb], acc10, 0, 0, 0);
            acc11 = __builtin_amdgcn_mfma_f32_16x16x32_bf16(af1, bfr[1][kb], acc11, 0, 0, 0);
        }

        float pr0[4], pr1[4];
        #pragma unroll
        for (int r = 0; r < 4; r++){
            pr0[r] = silu_f(acc00[r] + b2v0) * w3v0 + silu_f(acc01[r] + b2v1) * w3v1;
            pr1[r] = silu_f(acc10[r] + b2v0) * w3v0 + silu_f(acc11[r] + b2v1) * w3v1;
        }
        #pragma unroll
        for (int r = 0; r < 4; r++){
            #pragma unroll
            for (int m = 8; m >= 1; m >>= 1){
                pr0[r] += __shfl_xor(pr0[r], m, 64);
                pr1[r] += __shfl_xor(pr1[r], m, 64);
            }
        }
        if (lm == 0){
            #pragma unroll
            for (int r = 0; r < 4; r++){
                part[w][lq*4 + r]      = pr0[r];
                part[w][16 + lq*4 + r] = pr1[r];
            }
        }
        __syncthreads();

        if (t < 32 && (e0b + t) < E){
            float tot = part[0][t] + part[1][t] + part[2][t] + part[3][t] + b3;
            atomicAdd(&rho[pp_l[t]], tot * rc4_l[t].w);
        }
        __syncthreads();
    }
}

extern "C" void kernel_launch(void* const* d_in, const int* in_sizes, int n_in,
                              void* d_out, int out_size, void* d_ws, size_t ws_size,
                              hipStream_t stream)
{
    const float* s_stack   = (const float*)d_in[0];
    const float* v_stack   = (const float*)d_in[1];
    const float* atom_xyz  = (const float*)d_in[2];
    const float* probe_xyz = (const float*)d_in[3];
    const float* cell      = (const float*)d_in[4];
    const float* disp      = (const float*)d_in[5];
    const float* attn_w1   = (const float*)d_in[6];
    const float* attn_b1   = (const float*)d_in[7];
    const float* attn_w2   = (const float*)d_in[8];
    const float* msg_w1    = (const float*)d_in[10];
    const float* msg_b1    = (const float*)d_in[11];
    const float* msg_w2    = (const float*)d_in[12];
    const float* msg_b2    = (const float*)d_in[13];
    const float* msg_w3    = (const float*)d_in[14];
    const float* msg_b3    = (const float*)d_in[15];
    const int*   pe        = (const int*)d_in[16];

    const int N = in_sizes[0] / (L_DIM * F_DIM);
    const int E = in_sizes[16] / 2;
    const int P = out_size;
    const size_t NF = (size_t)N * F_DIM;

    float* ws = (float*)d_ws;
    unsigned short* VJKb = (unsigned short*)ws;            // 3N x 256 bf16 (1.5 NF fl)
    unsigned short* NISb = VJKb + 3*NF;                    // N x 512 bf16  (1.0 NF fl)
    float* UT4 = ws + (5*NF)/2;                            // N x 256 x 4 f32 (4 NF fl)
    unsigned short* w1bt  = (unsigned short*)(ws + (13*NF)/2);  // 256x256 bf16
    unsigned short* w1cdt = w1bt + 65536;                  // 256x512 bf16
    unsigned short* w2t   = w1cdt + 131072;                // 128x256 bf16
    unsigned short* wA1t  = w2t + 32768;                   // 128x256 bf16
    int* cnt  = (int*)(wA1t + 32768);
    int* pos  = cnt + N;
    int* offs = pos + N;
    int* perm = offs + N + 1;

    // kPrep grid: 262144 weight elems + 32768 rho zero + 2N cnt/pos zero
    const int prepElems = 262144 + 32768 + 2 * N;
    kPrep<<<(prepElems + 255) / 256, 256, 0, stream>>>(
        msg_w1, msg_w2, attn_w1, w1bt, w1cdt, w2t, wA1t,
        (float*)d_out, P, cnt, 2 * N);

    kAW<<<(N + 15) / 16, 256, 0, stream>>>(s_stack, v_stack, wA1t, attn_b1, attn_w2,
                                           VJKb, NISb, N);

    const int gU = (3 * N) / 128;                          // 192
    const int gT = (N / 128) * 2;                          // 128
    kA2<<<gU + gT, 256, 0, stream>>>(VJKb, w1bt, NISb, w1cdt, msg_b1, UT4, gU);

    const int gE = (E + 255) / 256;
    kHist<<<gE, 256, 0, stream>>>(pe, cnt, E);
    kScan<<<1, 1024, 0, stream>>>(cnt, offs, N);
    kScatter<<<gE, 256, 0, stream>>>(pe, offs, pos, perm, E);

    kB1<<<(E + 127) / 128, 256, 0, stream>>>(pe, disp, cell, atom_xyz, probe_xyz,
                                             UT4, msg_w1,
                                             w2t, msg_b2, msg_w3, msg_b3,
                                             perm, (float*)d_out, E);
}

// Round 11
// 186.778 us; speedup vs baseline: 1.3036x; 1.0194x over previous
//
#include <hip/hip_runtime.h>
#include <math.h>
#include <stdint.h>

// PaiNN QM encoder, round 11.
//   U = V_JK @ W1b  (N,3,256)   T = b1 + n_i@W1c + S_JK@W1d  (N,256)
//   per edge: x = silu(T[i] + e_pi@W1a + r_hat.U[i]); m = (silu(x@W2+b2))@w3+b3
// r11: kAW re-gridded for occupancy -- 8 atoms/block (1024 blocks, was 512):
// phase 1 = 3 MFMA m-tiles, phase 2 = 2 atoms/wave. kAW was 112us profiled at
// 20% occupancy / 1.3 TB/s (grid-starved). Everything else identical to r10.

#define L_DIM 6
#define F_DIM 256
#define FH_DIM 128
#define DRBF 32
#define CUTOFF_F 4.0f
#define PI_F 3.14159265358979323846f

using bf16x8 = __attribute__((ext_vector_type(8))) short;
using f32x4v = __attribute__((ext_vector_type(4))) float;

__device__ __forceinline__ float silu_f(float x){ return x / (1.f + __expf(-x)); }

__device__ __forceinline__ unsigned short f2bf(float f){
    uint32_t u = __float_as_uint(f);
    uint32_t r = (u + 0x7fffu + ((u >> 16) & 1u)) >> 16;   // RNE
    return (unsigned short)r;
}

// ---------------- kPrep: weight transpose/convert + output/CSR zeroing ----------------
__global__ __launch_bounds__(256) void kPrep(
    const float* __restrict__ msg_w1, const float* __restrict__ msg_w2,
    const float* __restrict__ attn_w1,
    unsigned short* __restrict__ w1bt, unsigned short* __restrict__ w1cdt,
    unsigned short* __restrict__ w2t, unsigned short* __restrict__ wA1t,
    float* __restrict__ rho, int P, int* __restrict__ cntpos, int CN)
{
    int idx = blockIdx.x * 256 + threadIdx.x;
    if (idx < 65536){
        int k = idx >> 8, j = idx & 255;
        w1bt[(size_t)j * 256 + k] = f2bf(msg_w1[(size_t)(DRBF + k) * F_DIM + j]);
    } else if (idx < 196608){
        int i2 = idx - 65536;
        int k = i2 >> 8, j = i2 & 255;
        w1cdt[(size_t)j * 512 + k] = f2bf(msg_w1[(size_t)(DRBF + 256 + k) * F_DIM + j]);
    } else if (idx < 229376){
        int i3 = idx - 196608;
        int k = i3 >> 7, h = i3 & 127;
        w2t[(size_t)h * 256 + k] = f2bf(msg_w2[(size_t)k * FH_DIM + h]);
    } else if (idx < 262144){
        int i4 = idx - 229376;
        int j = i4 >> 8, k = i4 & 255;
        wA1t[(size_t)j * 256 + k] = f2bf(attn_w1[(size_t)k * FH_DIM + j]);
    } else if (idx < 262144 + 32768){
        int i5 = idx - 262144;
        if (i5 < P) rho[i5] = 0.f;
    } else {
        int i6 = idx - 262144 - 32768;
        if (i6 < CN) cntpos[i6] = 0;
    }
}

// ---------------- kAW: fused attention, 8 atoms/block (r11 re-grid) ----------------
__global__ __launch_bounds__(256) void kAW(
    const float* __restrict__ s_stack, const float* __restrict__ v_stack,
    const unsigned short* __restrict__ wA1t,
    const float* __restrict__ attn_b1, const float* __restrict__ attn_w2,
    unsigned short* __restrict__ VJKb, unsigned short* __restrict__ NISb, int N)
{
    __shared__ float part[4][48];
    __shared__ float aw_l[8][8];

    const int t  = threadIdx.x;
    const int l  = t & 63;
    const int w  = t >> 6;
    const int lm = l & 15, lq = l >> 4;

    bf16x8 bfr[2][8];
    #pragma unroll
    for (int nt2 = 0; nt2 < 2; nt2++){
        const int col = w*32 + nt2*16 + lm;
        #pragma unroll
        for (int kb = 0; kb < 8; kb++)
            bfr[nt2][kb] = *(const bf16x8*)(wA1t + (size_t)col * 256 + kb*32 + lq*8);
    }
    const float b1a = attn_b1[w*32 + lm];
    const float b1b = attn_b1[w*32 + 16 + lm];
    const float w2a = attn_w2[w*32 + lm];
    const float w2b = attn_w2[w*32 + 16 + lm];

    const int n0 = blockIdx.x * 8;
    const size_t rbase = (size_t)n0 * L_DIM;
    const size_t rmax  = (size_t)N * L_DIM - 1;

    // ---- phase 1: logits (48 rows = 3 m-tiles) ----
    #pragma unroll
    for (int mt = 0; mt < 3; mt++){
        const size_t r0 = rbase + mt * 16;
        bf16x8 af[8];
        #pragma unroll
        for (int kb = 0; kb < 8; kb++){
            size_t row = r0 + lm; if (row > rmax) row = rmax;
            const float* ap = s_stack + row * 256 + kb*32 + lq*8;
            float4 fa = *(const float4*)ap;
            float4 fb = *(const float4*)(ap + 4);
            bf16x8 v;
            v[0] = (short)f2bf(fa.x); v[1] = (short)f2bf(fa.y);
            v[2] = (short)f2bf(fa.z); v[3] = (short)f2bf(fa.w);
            v[4] = (short)f2bf(fb.x); v[5] = (short)f2bf(fb.y);
            v[6] = (short)f2bf(fb.z); v[7] = (short)f2bf(fb.w);
            af[kb] = v;
        }
        f32x4v a0 = {0.f,0.f,0.f,0.f}, a1 = {0.f,0.f,0.f,0.f};
        #pragma unroll
        for (int kb = 0; kb < 8; kb++){
            a0 = __builtin_amdgcn_mfma_f32_16x16x32_bf16(af[kb], bfr[0][kb], a0, 0, 0, 0);
            a1 = __builtin_amdgcn_mfma_f32_16x16x32_bf16(af[kb], bfr[1][kb], a1, 0, 0, 0);
        }
        #pragma unroll
        for (int r = 0; r < 4; r++){
            float p = silu_f(a0[r] + b1a) * w2a + silu_f(a1[r] + b1b) * w2b;
            #pragma unroll
            for (int m = 8; m >= 1; m >>= 1) p += __shfl_xor(p, m, 64);
            if (lm == 0) part[w][mt*16 + lq*4 + r] = p;
        }
    }
    __syncthreads();
    if (t < 48) part[0][t] = part[0][t] + part[1][t] + part[2][t] + part[3][t];
    __syncthreads();
    if (t < 8){
        float e[L_DIM]; float mx = -1e30f;
        #pragma unroll
        for (int l6 = 0; l6 < L_DIM; l6++) mx = fmaxf(mx, part[0][t*L_DIM + l6]);
        float s = 0.f;
        #pragma unroll
        for (int l6 = 0; l6 < L_DIM; l6++){ e[l6] = __expf(part[0][t*L_DIM + l6] - mx); s += e[l6]; }
        float inv = 1.f / s;
        #pragma unroll
        for (int l6 = 0; l6 < L_DIM; l6++) aw_l[t][l6] = e[l6] * inv;
    }
    __syncthreads();

    // ---- phase 2: weighted sums (wave handles 2 atoms, fully unrolled) ----
    #pragma unroll
    for (int aa = 0; aa < 2; aa++){
        const int n = min(n0 + w*2 + aa, N - 1);
        float aw[L_DIM];
        #pragma unroll
        for (int l6 = 0; l6 < L_DIM; l6++) aw[l6] = aw_l[w*2 + aa][l6];

        const float* sp = s_stack + (size_t)n * (L_DIM * F_DIM) + l * 4;
        const float* vp = v_stack + (size_t)n * (L_DIM * 3 * F_DIM) + l * 4;
        float4 v0 = {0.f,0.f,0.f,0.f}, v1 = {0.f,0.f,0.f,0.f}, v2 = {0.f,0.f,0.f,0.f};
        float4 sj = {0.f,0.f,0.f,0.f};
        #pragma unroll
        for (int l6 = 0; l6 < L_DIM; l6++){
            const float a = aw[l6];
            float4 ss = *(const float4*)(sp + (size_t)l6 * F_DIM);
            float4 x0 = *(const float4*)(vp + (size_t)(l6*3+0) * F_DIM);
            float4 x1 = *(const float4*)(vp + (size_t)(l6*3+1) * F_DIM);
            float4 x2 = *(const float4*)(vp + (size_t)(l6*3+2) * F_DIM);
            v0.x = fmaf(a, x0.x, v0.x); v0.y = fmaf(a, x0.y, v0.y);
            v0.z = fmaf(a, x0.z, v0.z); v0.w = fmaf(a, x0.w, v0.w);
            v1.x = fmaf(a, x1.x, v1.x); v1.y = fmaf(a, x1.y, v1.y);
            v1.z = fmaf(a, x1.z, v1.z); v1.w = fmaf(a, x1.w, v1.w);
            v2.x = fmaf(a, x2.x, v2.x); v2.y = fmaf(a, x2.y, v2.y);
            v2.z = fmaf(a, x2.z, v2.z); v2.w = fmaf(a, x2.w, v2.w);
            sj.x = fmaf(a, ss.x, sj.x); sj.y = fmaf(a, ss.y, sj.y);
            sj.z = fmaf(a, ss.z, sj.z); sj.w = fmaf(a, ss.w, sj.w);
        }
        float4 ni;
        ni.x = sqrtf(v0.x*v0.x + v1.x*v1.x + v2.x*v2.x);
        ni.y = sqrtf(v0.y*v0.y + v1.y*v1.y + v2.y*v2.y);
        ni.z = sqrtf(v0.z*v0.z + v1.z*v1.z + v2.z*v2.z);
        ni.w = sqrtf(v0.w*v0.w + v1.w*v1.w + v2.w*v2.w);

        ushort4 o;
        o = (ushort4){f2bf(v0.x), f2bf(v0.y), f2bf(v0.z), f2bf(v0.w)};
        *(ushort4*)&VJKb[((size_t)n*3 + 0) * F_DIM + l*4] = o;
        o = (ushort4){f2bf(v1.x), f2bf(v1.y), f2bf(v1.z), f2bf(v1.w)};
        *(ushort4*)&VJKb[((size_t)n*3 + 1) * F_DIM + l*4] = o;
        o = (ushort4){f2bf(v2.x), f2bf(v2.y), f2bf(v2.z), f2bf(v2.w)};
        *(ushort4*)&VJKb[((size_t)n*3 + 2) * F_DIM + l*4] = o;
        o = (ushort4){f2bf(ni.x), f2bf(ni.y), f2bf(ni.z), f2bf(ni.w)};
        *(ushort4*)&NISb[(size_t)n * 512 + l*4] = o;
        o = (ushort4){f2bf(sj.x), f2bf(sj.y), f2bf(sj.z), f2bf(sj.w)};
        *(ushort4*)&NISb[(size_t)n * 512 + 256 + l*4] = o;
    }
}

// ---------------- kA2: merged U (blocks < gU) and T (blocks >= gU) -> UT4 ----------------
__global__ __launch_bounds__(256) void kA2(
    const unsigned short* __restrict__ VJKb, const unsigned short* __restrict__ w1bt,
    const unsigned short* __restrict__ NISb, const unsigned short* __restrict__ w1cdt,
    const float* __restrict__ msg_b1,
    float* __restrict__ UT4, int gU)
{
    const int t  = threadIdx.x;
    const int l  = t & 63;
    const int w  = t >> 6;
    const int lm = l & 15, lq = l >> 4;

    if ((int)blockIdx.x < gU){
        bf16x8 bfr[4][8];
        #pragma unroll
        for (int ct = 0; ct < 4; ct++)
            #pragma unroll
            for (int kb = 0; kb < 8; kb++)
                bfr[ct][kb] = *(const bf16x8*)(w1bt + (size_t)(w*64 + ct*16 + lm) * 256 + kb*32 + lq*8);

        const int r00 = blockIdx.x * 128;
        #pragma unroll 1
        for (int mt = 0; mt < 8; mt++){
            const int r0 = r00 + mt * 16;
            bf16x8 af[8];
            #pragma unroll
            for (int kb = 0; kb < 8; kb++)
                af[kb] = *(const bf16x8*)(VJKb + (size_t)(r0 + lm) * 256 + kb*32 + lq*8);
            f32x4v acc[4];
            #pragma unroll
            for (int ct = 0; ct < 4; ct++) acc[ct] = (f32x4v){0.f,0.f,0.f,0.f};
            #pragma unroll
            for (int kb = 0; kb < 8; kb++)
                #pragma unroll
                for (int ct = 0; ct < 4; ct++)
                    acc[ct] = __builtin_amdgcn_mfma_f32_16x16x32_bf16(af[kb], bfr[ct][kb], acc[ct], 0, 0, 0);
            #pragma unroll
            for (int ct = 0; ct < 4; ct++){
                const int col = w*64 + ct*16 + lm;
                #pragma unroll
                for (int r = 0; r < 4; r++){
                    const int row = r0 + lq*4 + r;
                    const int n = row / 3, c = row - n*3;
                    UT4[(((size_t)n << 8) + col) * 4 + c] = acc[ct][r];
                }
            }
        }
    } else {
        const int bid = blockIdx.x - gU;
        const int ch = bid & 1;
        const int bm = bid >> 1;

        bf16x8 bfr[2][16];
        #pragma unroll
        for (int ct = 0; ct < 2; ct++)
            #pragma unroll
            for (int kb = 0; kb < 16; kb++)
                bfr[ct][kb] = *(const bf16x8*)(w1cdt + (size_t)(ch*128 + w*32 + ct*16 + lm) * 512 + kb*32 + lq*8);

        const int r00 = bm * 128;
        #pragma unroll 1
        for (int mt = 0; mt < 8; mt++){
            const int r0 = r00 + mt * 16;
            bf16x8 af[16];
            #pragma unroll
            for (int kb = 0; kb < 16; kb++)
                af[kb] = *(const bf16x8*)(NISb + (size_t)(r0 + lm) * 512 + kb*32 + lq*8);
            f32x4v acc[2];
            #pragma unroll
            for (int ct = 0; ct < 2; ct++) acc[ct] = (f32x4v){0.f,0.f,0.f,0.f};
            #pragma unroll
            for (int kb = 0; kb < 16; kb++)
                #pragma unroll
                for (int ct = 0; ct < 2; ct++)
                    acc[ct] = __builtin_amdgcn_mfma_f32_16x16x32_bf16(af[kb], bfr[ct][kb], acc[ct], 0, 0, 0);
            #pragma unroll
            for (int ct = 0; ct < 2; ct++){
                const int col = ch*128 + w*32 + ct*16 + lm;
                const float bias = msg_b1[col];
                #pragma unroll
                for (int r = 0; r < 4; r++){
                    const int n = r0 + lq*4 + r;
                    UT4[(((size_t)n << 8) + col) * 4 + 3] = acc[ct][r] + bias;
                }
            }
        }
    }
}

// ---------------- CSR binning ----------------
__global__ __launch_bounds__(256) void kHist(const int* __restrict__ pe, int* __restrict__ cnt, int E){
    int e = blockIdx.x * 256 + threadIdx.x;
    if (e < E) atomicAdd(&cnt[pe[(size_t)e*2]], 1);
}

__global__ __launch_bounds__(1024) void kScan(const int* __restrict__ cnt, int* __restrict__ off, int N){
    __shared__ int sums[1024];
    const int t = threadIdx.x;
    const int base = t * 8;
    int c[8]; int s = 0;
    #pragma unroll
    for (int j = 0; j < 8; j++){
        int v = (base + j < N) ? cnt[base + j] : 0;
        c[j] = s; s += v;
    }
    sums[t] = s;
    __syncthreads();
    for (int d = 1; d < 1024; d <<= 1){
        int v = (t >= d) ? sums[t - d] : 0;
        __syncthreads();
        sums[t] += v;
        __syncthreads();
    }
    int excl = (t == 0) ? 0 : sums[t - 1];
    #pragma unroll
    for (int j = 0; j < 8; j++)
        if (base + j < N) off[base + j] = excl + c[j];
    if (t == 1023) off[N] = sums[1023];
}

__global__ __launch_bounds__(256) void kScatter(const int* __restrict__ pe,
    const int* __restrict__ off, int* __restrict__ pos, int* __restrict__ perm, int E){
    int e = blockIdx.x * 256 + threadIdx.x;
    if (e < E){
        int i = pe[(size_t)e*2];
        int slot = atomicAdd(&pos[i], 1);
        perm[off[i] + slot] = e;
    }
}

// ---------------- kB1: fused geometry + edge MLP + scatter (r8/r10 version) ----------------
__global__ __launch_bounds__(256) void kB1(
    const int* __restrict__ pe, const float* __restrict__ disp,
    const float* __restrict__ cell,
    const float* __restrict__ atom_xyz, const float* __restrict__ probe_xyz,
    const float* __restrict__ UT4,
    const float* __restrict__ msg_w1,
    const unsigned short* __restrict__ w2t, const float* __restrict__ msg_b2,
    const float* __restrict__ msg_w3, const float* __restrict__ msg_b3,
    const int* __restrict__ perm,
    float* __restrict__ rho, int E)
{
    __shared__ unsigned short x_lds[32 * 256];   // 16 KB, XOR-swizzled
    __shared__ unsigned short epi_b[32 * 40];    // 2.5 KB, bf16 A-tile (pad 40)
    __shared__ int   ai_l[32];
    __shared__ int   pp_l[32];
    __shared__ float4 rc4_l[32];
    __shared__ float part[4][32];

    char* xbase = (char*)x_lds;

    const int t  = threadIdx.x;
    const int l  = t & 63;
    const int w  = t >> 6;
    const int lq = l >> 4;
    const int lm = l & 15;

    const float c0 = cell[0], c1 = cell[1], c2 = cell[2];
    const float c3 = cell[3], c4 = cell[4], c5 = cell[5];
    const float c6 = cell[6], c7 = cell[7], c8 = cell[8];

    bf16x8 w1afr[4];
    #pragma unroll
    for (int nt = 0; nt < 4; nt++){
        const int col = w*64 + nt*16 + lm;
        bf16x8 v;
        #pragma unroll
        for (int j = 0; j < 8; j++)
            v[j] = (short)f2bf(msg_w1[(size_t)(lq*8 + j) * F_DIM + col]);
        w1afr[nt] = v;
    }

    bf16x8 bfr[2][8];
    #pragma unroll
    for (int nt2 = 0; nt2 < 2; nt2++){
        const int h = w*32 + nt2*16 + lm;
        #pragma unroll
        for (int kb = 0; kb < 8; kb++)
            bfr[nt2][kb] = *(const bf16x8*)(w2t + (size_t)h * F_DIM + kb*32 + lq*8);
    }
    const float b2v0 = msg_b2[w*32 + lm];
    const float b2v1 = msg_b2[w*32 + 16 + lm];
    const float w3v0 = msg_w3[w*32 + lm];
    const float w3v1 = msg_w3[w*32 + 16 + lm];
    const float b3   = msg_b3[0];

    const int e0 = blockIdx.x * 128;

    int ee_r[4], ia_r[4], ip_r[4];
    #pragma unroll
    for (int bb = 0; bb < 4; bb++){
        int s = min(e0 + bb*32 + (t >> 3), E - 1);
        ee_r[bb] = perm[s];
    }
    #pragma unroll
    for (int bb = 0; bb < 4; bb++){
        ia_r[bb] = pe[(size_t)ee_r[bb]*2];
        ip_r[bb] = pe[(size_t)ee_r[bb]*2 + 1];
    }

    #pragma unroll 1
    for (int bb = 0; bb < 4; bb++){
        const int e0b = e0 + bb * 32;

        {
            const int slot = t >> 3, q = t & 7;
            const int ee = ee_r[bb];
            const int ia = ia_r[bb];
            const int ip = ip_r[bb];
            const float d0 = disp[(size_t)ee*3], d1 = disp[(size_t)ee*3+1], d2 = disp[(size_t)ee*3+2];
            const float sx = d0*c0 + d1*c3 + d2*c6;
            const float sy = d0*c1 + d1*c4 + d2*c7;
            const float sz = d0*c2 + d1*c5 + d2*c8;
            const float dx = probe_xyz[(size_t)ip*3+0] - (atom_xyz[(size_t)ia*3+0] + sx);
            const float dy = probe_xyz[(size_t)ip*3+1] - (atom_xyz[(size_t)ia*3+1] + sy);
            const float dz = probe_xyz[(size_t)ip*3+2] - (atom_xyz[(size_t)ia*3+2] + sz);
            const float dist = sqrtf(dx*dx + dy*dy + dz*dz);
            const float inv  = 1.f / (dist + 1e-8f);
            const float base = dist * (PI_F / CUTOFF_F);
            ushort4 eb;
            eb.x = f2bf(__sinf(base * (float)(q*4 + 1)) * inv);
            eb.y = f2bf(__sinf(base * (float)(q*4 + 2)) * inv);
            eb.z = f2bf(__sinf(base * (float)(q*4 + 3)) * inv);
            eb.w = f2bf(__sinf(base * (float)(q*4 + 4)) * inv);
            *(ushort4*)&epi_b[slot*40 + q*4] = eb;
            if (q == 0){
                ai_l[slot] = ia;
                pp_l[slot] = ip;
                float cw = (dist < CUTOFF_F) ? 0.5f * (__cosf(base) + 1.f) : 0.f;
                rc4_l[slot] = (float4){dx*inv, dy*inv, dz*inv, cw};
            }
        }
        __syncthreads();

        f32x4v pacc[2][4];
        #pragma unroll
        for (int mt = 0; mt < 2; mt++)
            #pragma unroll
            for (int nt = 0; nt < 4; nt++) pacc[mt][nt] = (f32x4v){0.f,0.f,0.f,0.f};
        #pragma unroll
        for (int mt = 0; mt < 2; mt++){
            const bf16x8 af = *(const bf16x8*)&epi_b[(mt*16 + lm)*40 + lq*8];
            #pragma unroll
            for (int nt = 0; nt < 4; nt++)
                pacc[mt][nt] = __builtin_amdgcn_mfma_f32_16x16x32_bf16(af, w1afr[nt], pacc[mt][nt], 0, 0, 0);
        }

        #pragma unroll
        for (int mt = 0; mt < 2; mt++){
            #pragma unroll
            for (int r = 0; r < 4; r++){
                const int e = mt*16 + lq*4 + r;
                const int i = ai_l[e];
                const float4 rc = rc4_l[e];
                const float* up = UT4 + ((size_t)i << 10);
                #pragma unroll
                for (int nt = 0; nt < 4; nt++){
                    const int col = w*64 + nt*16 + lm;
                    const float4 ut = *(const float4*)(up + (size_t)col * 4);
                    float z = pacc[mt][nt][r] + ut.w;
                    z = fmaf(rc.x, ut.x, fmaf(rc.y, ut.y, fmaf(rc.z, ut.z, z)));
                    const int wofs = e*512 + ((col*2) ^ ((e & 7) << 4));
                    *(unsigned short*)(xbase + wofs) = f2bf(silu_f(z));
                }
            }
        }
        __syncthreads();

        f32x4v acc00 = {0.f,0.f,0.f,0.f}, acc01 = {0.f,0.f,0.f,0.f};
        f32x4v acc10 = {0.f,0.f,0.f,0.f}, acc11 = {0.f,0.f,0.f,0.f};
        const int eA0 = lm;
        const int eA1 = 16 + lm;
        #pragma unroll
        for (int kb = 0; kb < 8; kb++){
            const int ko = kb*64 + lq*16;
            bf16x8 af0 = *(const bf16x8*)(xbase + eA0*512 + (ko ^ ((eA0 & 7) << 4)));
            bf16x8 af1 = *(const bf16x8*)(xbase + eA1*512 + (ko ^ ((eA1 & 7) << 4)));
            acc00 = __builtin_amdgcn_mfma_f32_16x16x32_bf16(af0, bfr[0][kb], acc00, 0, 0, 0);
            acc01 = __builtin_amdgcn_mfma_f32_16x16x32_bf16(af0, bfr[1][kb], acc01, 0, 0, 0);
            acc10 = __builtin_amdgcn_mfma_f32_16x16x32_bf16(af1, bfr[0][kb], acc10, 0, 0, 0);
            acc11 = __builtin_amdgcn_mfma_f32_16x16x32_bf16(af1, bfr[1][kb], acc11, 0, 0, 0);
        }

        float pr0[4], pr1[4];
        #pragma unroll
        for (int r = 0; r < 4; r++){
            pr0[r] = silu_f(acc00[r] + b2v0) * w3v0 + silu_f(acc01[r] + b2v1) * w3v1;
            pr1[r] = silu_f(acc10[r] + b2v0) * w3v0 + silu_f(acc11[r] + b2v1) * w3v1;
        }
        #pragma unroll
        for (int r = 0; r < 4; r++){
            #pragma unroll
            for (int m = 8; m >= 1; m >>= 1){
                pr0[r] += __shfl_xor(pr0[r], m, 64);
                pr1[r] += __shfl_xor(pr1[r], m, 64);
            }
        }
        if (lm == 0){
            #pragma unroll
            for (int r = 0; r < 4; r++){
                part[w][lq*4 + r]      = pr0[r];
                part[w][16 + lq*4 + r] = pr1[r];
            }
        }
        __syncthreads();

        if (t < 32 && (e0b + t) < E){
            float tot = part[0][t] + part[1][t] + part[2][t] + part[3][t] + b3;
            atomicAdd(&rho[pp_l[t]], tot * rc4_l[t].w);
        }
        __syncthreads();
    }
}

extern "C" void kernel_launch(void* const* d_in, const int* in_sizes, int n_in,
                              void* d_out, int out_size, void* d_ws, size_t ws_size,
                              hipStream_t stream)
{
    const float* s_stack   = (const float*)d_in[0];
    const float* v_stack   = (const float*)d_in[1];
    const float* atom_xyz  = (const float*)d_in[2];
    const float* probe_xyz = (const float*)d_in[3];
    const float* cell      = (const float*)d_in[4];
    const float* disp      = (const float*)d_in[5];
    const float* attn_w1   = (const float*)d_in[6];
    const float* attn_b1   = (const float*)d_in[7];
    const float* attn_w2   = (const float*)d_in[8];
    const float* msg_w1    = (const float*)d_in[10];
    const float* msg_b1    = (const float*)d_in[11];
    const float* msg_w2    = (const float*)d_in[12];
    const float* msg_b2    = (const float*)d_in[13];
    const float* msg_w3    = (const float*)d_in[14];
    const float* msg_b3    = (const float*)d_in[15];
    const int*   pe        = (const int*)d_in[16];

    const int N = in_sizes[0] / (L_DIM * F_DIM);
    const int E = in_sizes[16] / 2;
    const int P = out_size;
    const size_t NF = (size_t)N * F_DIM;

    float* ws = (float*)d_ws;
    unsigned short* VJKb = (unsigned short*)ws;            // 3N x 256 bf16 (1.5 NF fl)
    unsigned short* NISb = VJKb + 3*NF;                    // N x 512 bf16  (1.0 NF fl)
    float* UT4 = ws + (5*NF)/2;                            // N x 256 x 4 f32 (4 NF fl)
    unsigned short* w1bt  = (unsigned short*)(ws + (13*NF)/2);  // 256x256 bf16
    unsigned short* w1cdt = w1bt + 65536;                  // 256x512 bf16
    unsigned short* w2t   = w1cdt + 131072;                // 128x256 bf16
    unsigned short* wA1t  = w2t + 32768;                   // 128x256 bf16
    int* cnt  = (int*)(wA1t + 32768);
    int* pos  = cnt + N;
    int* offs = pos + N;
    int* perm = offs + N + 1;

    const int prepElems = 262144 + 32768 + 2 * N;
    kPrep<<<(prepElems + 255) / 256, 256, 0, stream>>>(
        msg_w1, msg_w2, attn_w1, w1bt, w1cdt, w2t, wA1t,
        (float*)d_out, P, cnt, 2 * N);

    kAW<<<(N + 7) / 8, 256, 0, stream>>>(s_stack, v_stack, wA1t, attn_b1, attn_w2,
                                         VJKb, NISb, N);

    const int gU = (3 * N) / 128;                          // 192
    const int gT = (N / 128) * 2;                          // 128
    kA2<<<gU + gT, 256, 0, stream>>>(VJKb, w1bt, NISb, w1cdt, msg_b1, UT4, gU);

    const int gE = (E + 255) / 256;
    kHist<<<gE, 256, 0, stream>>>(pe, cnt, E);
    kScan<<<1, 1024, 0, stream>>>(cnt, offs, N);
    kScatter<<<gE, 256, 0, stream>>>(pe, offs, pos, perm, E);

    kB1<<<(E + 127) / 128, 256, 0, stream>>>(pe, disp, cell, atom_xyz, probe_xyz,
                                             UT4, msg_w1,
                                             w2t, msg_b2, msg_w3, msg_b3,
                                             perm, (float*)d_out, E);
}